// Round 1
// baseline (2129.452 us; speedup 1.0000x reference)
//
#include <hip/hip_runtime.h>
#include <hip/hip_bf16.h>

#define NN 50000
#define RR 8
#define EE 200000
#define EDD 400000
#define SCB 196   // ceil(NN/256) scan blocks

typedef __attribute__((ext_vector_type(8))) short short8;
typedef __attribute__((ext_vector_type(4))) float floatx4;

static __device__ __forceinline__ unsigned short f2bf(float f) {
    union { float f; unsigned u; } v; v.f = f;
    unsigned r = v.u + 0x7fff + ((v.u >> 16) & 1);
    return (unsigned short)(r >> 16);
}
static __device__ __forceinline__ float bf2f(unsigned short h) {
    union { unsigned u; float f; } v; v.u = ((unsigned)h) << 16;
    return v.f;
}
// async global->LDS, 16B per lane; LDS dest = uniform base + lane*16
static __device__ __forceinline__ void gload_lds16(const unsigned short* g, unsigned short* l) {
    __builtin_amdgcn_global_load_lds(
        (const __attribute__((address_space(1))) void*)g,
        (__attribute__((address_space(3))) void*)l,
        16, 0, 0);
}

// ---------------- degree histogram: direct global atomics ----------------
// 3.2M atomics over 400K ints (avg 4/address) beats LDS privatization here:
// privatized flush was issuing ~4M global atomics anyway, at 1 block/CU.
__global__ void k_hist(const int* __restrict__ src, const int* __restrict__ dst,
                       int* __restrict__ outdeg, int* __restrict__ indeg) {
    int i = blockIdx.x * blockDim.x + threadIdx.x;
    if (i >= RR * EE) return;
    int r = i / EE;
    int base = r * NN;
    atomicAdd(&outdeg[base + src[i]], 1);
    atomicAdd(&indeg[base + dst[i]], 1);
}

// ---------------- norms: in-place int degree -> float rsqrt ----------------
__global__ void k_norms(int* __restrict__ outdeg, int* __restrict__ indeg) {
    int i = blockIdx.x * blockDim.x + threadIdx.x;
    if (i >= RR * NN) return;
    int od = outdeg[i];
    int id = indeg[i];
    ((float*)outdeg)[i] = od > 0 ? rsqrtf((float)od) : 0.f;
    ((float*)indeg)[i]  = id > 0 ? rsqrtf((float)id) : 0.f;
}

// ---------------- parallel scan: phase A (per-block sums) ----------------
__global__ void k_scanA(const int* __restrict__ indeg, int* __restrict__ bsum) {
    int r = blockIdx.y;
    int i = blockIdx.x * 256 + threadIdx.x;
    int v = (i < NN) ? indeg[(size_t)r * NN + i] : 0;
    #pragma unroll
    for (int d = 32; d > 0; d >>= 1) v += __shfl_down(v, d, 64);
    __shared__ int ws4[4];
    if ((threadIdx.x & 63) == 0) ws4[threadIdx.x >> 6] = v;
    __syncthreads();
    if (threadIdx.x == 0) bsum[r * SCB + blockIdx.x] = ws4[0] + ws4[1] + ws4[2] + ws4[3];
}

// ---------------- phase B: exclusive scan of SCB block sums per relation ----------------
__global__ void k_scanB(int* __restrict__ bsum, int* __restrict__ offs) {
    int r = blockIdx.x;
    int t = threadIdx.x;
    int v = (t < SCB) ? bsum[r * SCB + t] : 0;
    int lane = t & 63, wid = t >> 6;
    int sv = v;
    #pragma unroll
    for (int d = 1; d < 64; d <<= 1) {
        int u = __shfl_up(sv, d, 64);
        if (lane >= d) sv += u;
    }
    __shared__ int wsum[4];
    if (lane == 63) wsum[wid] = sv;
    __syncthreads();
    int add = 0;
    for (int x = 0; x < wid; x++) add += wsum[x];
    int incl = sv + add;
    if (t < SCB) bsum[r * SCB + t] = incl - v;
    if (t == 255) offs[(size_t)r * (NN + 1) + NN] = incl;  // grand total
}

// ---------------- phase C: intra-block exclusive scan + base ----------------
__global__ void k_scanC(const int* __restrict__ indeg, const int* __restrict__ bsum,
                        int* __restrict__ offs) {
    int r = blockIdx.y;
    int i = blockIdx.x * 256 + threadIdx.x;
    int v = (i < NN) ? indeg[(size_t)r * NN + i] : 0;
    int lane = threadIdx.x & 63, wid = threadIdx.x >> 6;
    int sv = v;
    #pragma unroll
    for (int d = 1; d < 64; d <<= 1) {
        int u = __shfl_up(sv, d, 64);
        if (lane >= d) sv += u;
    }
    __shared__ int wsum[4];
    if (lane == 63) wsum[wid] = sv;
    __syncthreads();
    int add = bsum[r * SCB + blockIdx.x];
    for (int x = 0; x < wid; x++) add += wsum[x];
    if (i < NN) offs[(size_t)r * (NN + 1) + i] = sv - v + add;
}

// ---------------- fill CSR with fused src-norm weight: (src, ns[r][src]) ----------------
__global__ void k_fillw(const int* __restrict__ src, const int* __restrict__ dst,
                        const int* __restrict__ offs, const float* __restrict__ ns,
                        int* __restrict__ cursor, int2* __restrict__ csrw) {
    int i = blockIdx.x * blockDim.x + threadIdx.x;
    if (i >= RR * EE) return;
    int r = i / EE;
    int s = src[i], d = dst[i];
    int pos = offs[r * (NN + 1) + d] + atomicAdd(&cursor[r * NN + d], 1);
    int2 v;
    v.x = s;
    v.y = __float_as_int(ns[(size_t)r * NN + s]);
    csrw[(size_t)r * EE + pos] = v;
}

// ---------------- decoder prep (Mcat, cvec) + bias sums, one launch ----------------
__global__ void k_prep(const float* __restrict__ Wp1, const float* __restrict__ Wp2,
                       const float* __restrict__ bp1, const float* __restrict__ bp2,
                       const float* __restrict__ b2a, const float* __restrict__ b2b,
                       const float* __restrict__ b3a, const float* __restrict__ b3b,
                       float* __restrict__ Mcat, float* __restrict__ cvec,
                       float* __restrict__ bs) {
    int bx = blockIdx.x;
    if (bx < 16) {
        int t = bx * 256 + threadIdx.x;      // 4096 elements
        int i = t >> 4, j = t & 15;
        int half = j >> 3, jj = j & 7;
        const float* wrow = Wp1 + (size_t)(half * 256 + i) * 256;
        float s = 0.f;
        for (int k = 0; k < 256; k++) s += wrow[k] * Wp2[k * 8 + jj];
        Mcat[i * 16 + j] = s;
    } else if (bx == 16) {
        int j = threadIdx.x;
        if (j < 8) {
            float s = bp2[j];
            for (int k = 0; k < 256; k++) s += bp1[k] * Wp2[k * 8 + j];
            cvec[j] = s;
        }
    } else {
        int j = threadIdx.x;  // 256
        float s = 0.f;
        for (int r = 0; r < RR; r++) s += b2a[r * 256 + j];
        bs[j] = s;
        if (j < 128) {
            s = 0.f;
            for (int r = 0; r < RR; r++) s += b2b[r * 128 + j];
            bs[256 + j] = s;
        }
        s = 0.f;
        for (int r = 0; r < RR; r++) s += b3a[r * 256 + j];
        bs[512 + j] = s;
        if (j < 128) {
            s = 0.f;
            for (int r = 0; r < RR; r++) s += b3b[r * 128 + j];
            bs[768 + j] = s;
        }
    }
}

// ---------------- fp32 -> bf16 elementwise cast ----------------
__global__ void k_cast(const float* __restrict__ x, unsigned short* __restrict__ y, int total) {
    int i = blockIdx.x * blockDim.x + threadIdx.x;
    if (i < total) y[i] = f2bf(x[i]);
}

// ---------------- fp32 [NN x 300] -> bf16 [NN x 320] zero-padded cast ----------------
__global__ void k_cast_pad(const float* __restrict__ x, unsigned short* __restrict__ y) {
    int i = blockIdx.x * blockDim.x + threadIdx.x;
    if (i >= NN * 320) return;
    int row = i / 320, col = i - row * 320;
    y[i] = (col < 300) ? f2bf(x[row * 300 + col]) : (unsigned short)0;
}

// ---------------- all 4 weight transposes in one launch ----------------
// Layout per matrix: WT[n][r][kpad], bf16, zero-padded in k.
__global__ void k_wt4(const float* __restrict__ W2a, const float* __restrict__ W2b,
                      const float* __restrict__ W3a, const float* __restrict__ W3b,
                      unsigned short* __restrict__ WT2a, unsigned short* __restrict__ WT2b,
                      unsigned short* __restrict__ WT3a, unsigned short* __restrict__ WT3b) {
    const float* W; unsigned short* WT; int K0, Kpad, Nout;
    switch (blockIdx.y) {
        case 0:  W = W2a; WT = WT2a; K0 = 256; Kpad = 256; Nout = 256; break;
        case 1:  W = W2b; WT = WT2b; K0 = 256; Kpad = 256; Nout = 128; break;
        case 2:  W = W3a; WT = WT3a; K0 = 300; Kpad = 320; Nout = 256; break;
        default: W = W3b; WT = WT3b; K0 = 256; Kpad = 256; Nout = 128; break;
    }
    int i = blockIdx.x * 256 + threadIdx.x;
    int total = Nout * RR * Kpad;
    if (i >= total) return;
    int n = i / (RR * Kpad);
    int rem = i - n * (RR * Kpad);
    int r = rem / Kpad;
    int k = rem - r * Kpad;
    float v = (k < K0) ? W[((size_t)r * K0 + k) * Nout + n] : 0.f;
    WT[i] = f2bf(v);
}

// ---------------- FUSED aggregate + GEMM ----------------
// out[n, :] = act( sum_r nd_r[n] * (sum_{e in CSR(r,n)} ns_e * x[src_e, :]) @ W_r + bias )
// Tile: BM=64 rows x NOUT cols per block, 4 waves.
// A-tile [64 x 64-kslice] is gather-aggregated straight into swizzled LDS
// (no Y intermediate). B streamed via global_load_lds from bf16 WT (L2-resident).
// Gather lane layout: group g = lane>>3 owns one node-row, lane&7 owns 8 cols
// (one short8 = 128B coalesced per edge); divergent edge loop, 2-edge unroll.
template<int NOUT, bool ALAYER>
__global__ __launch_bounds__(256, 3) void k_fused(
        const unsigned short* __restrict__ xb, int xstride, int KR,
        const unsigned short* __restrict__ WT, int ldbt,
        const float* __restrict__ bias,
        const int2* __restrict__ csrw, const int* __restrict__ offs,
        const float* __restrict__ nd,
        void* __restrict__ out) {
    constexpr int TNW = NOUT / 32;          // col-tiles per wave
    __shared__ unsigned short As[64 * 64];  // 8 KB
    __shared__ unsigned short Bs[NOUT * 64];
    int m0 = blockIdx.x * 64;
    int t = threadIdx.x;
    int w = t >> 6, l = t & 63;
    int lr = l & 15, lg = l >> 4;
    int lrow = l >> 3;                 // staging row within 8-row segment
    int lch  = (l & 7) ^ lrow;         // swizzled source chunk for B staging
    int g = l >> 3, j = l & 7;         // gather: node group, col-octet
    int qm = (w >> 1) * 32;
    int qn = (w & 1) * (NOUT / 2);

    floatx4 acc[2][TNW];
    #pragma unroll
    for (int a = 0; a < 2; a++)
        #pragma unroll
        for (int b = 0; b < TNW; b++)
            acc[a][b] = (floatx4){0.f, 0.f, 0.f, 0.f};

    for (int r = 0; r < RR; r++) {
        const int2*  cs   = csrw + (size_t)r * EE;
        const int*   offr = offs + r * (NN + 1);
        const float* ndr  = nd + (size_t)r * NN;
        for (int kc = 0; kc < KR; kc += 64) {
            int kw = r * KR + kc;
            // ---- stage B (async, lands during gather) ----
            #pragma unroll
            for (int j2 = 0; j2 < TNW; j2++) {
                int seg = w * TNW + j2;    // NOUT/8 segments of 8 rows
                gload_lds16(WT + (size_t)(seg * 8 + lrow) * ldbt + kw + lch * 8,
                            &Bs[seg * 512]);
            }
            // ---- gather-aggregate A: wave w stages rows w*16 .. w*16+15 ----
            #pragma unroll
            for (int round = 0; round < 2; round++) {
                int rl = w * 16 + round * 8 + g;   // row within block tile
                int n = m0 + rl;
                float va[8];
                #pragma unroll
                for (int q = 0; q < 8; q++) va[q] = 0.f;
                float ndv = 0.f;
                int e = 0, e1 = 0;
                if (n < NN) { e = offr[n]; e1 = offr[n + 1]; ndv = ndr[n]; }
                const unsigned short* xcb = xb + kc + j * 8;
                for (; e + 2 <= e1; e += 2) {
                    int2 r0 = cs[e], r1 = cs[e + 1];
                    short8 v0 = *(const short8*)(xcb + (size_t)(unsigned)r0.x * xstride);
                    short8 v1 = *(const short8*)(xcb + (size_t)(unsigned)r1.x * xstride);
                    float f0 = __int_as_float(r0.y), f1 = __int_as_float(r1.y);
                    #pragma unroll
                    for (int q = 0; q < 8; q++)
                        va[q] += f0 * bf2f((unsigned short)v0[q])
                               + f1 * bf2f((unsigned short)v1[q]);
                }
                if (e < e1) {
                    int2 r0 = cs[e];
                    short8 v0 = *(const short8*)(xcb + (size_t)(unsigned)r0.x * xstride);
                    float f0 = __int_as_float(r0.y);
                    #pragma unroll
                    for (int q = 0; q < 8; q++)
                        va[q] += f0 * bf2f((unsigned short)v0[q]);
                }
                short8 ob;
                #pragma unroll
                for (int q = 0; q < 8; q++) ob[q] = (short)f2bf(va[q] * ndv);
                // swizzled store matching frag-read: As[row*64 + ((c^ (row&7))<<3) + (k&7)]
                *(short8*)&As[rl * 64 + ((j ^ (rl & 7)) << 3)] = ob;
            }
            __syncthreads();
            // ---- MFMA over this 64-k slice ----
            #pragma unroll
            for (int ks = 0; ks < 2; ks++) {
                int slot = ((ks * 4 + lg) ^ (lr & 7)) * 8;
                short8 af[2], bf[TNW];
                #pragma unroll
                for (int i = 0; i < 2; i++)
                    af[i] = *(const short8*)&As[(qm + i * 16 + lr) * 64 + slot];
                #pragma unroll
                for (int i = 0; i < TNW; i++)
                    bf[i] = *(const short8*)&Bs[(qn + i * 16 + lr) * 64 + slot];
                #pragma unroll
                for (int tm = 0; tm < 2; tm++)
                    #pragma unroll
                    for (int tn = 0; tn < TNW; tn++)
                        acc[tm][tn] = __builtin_amdgcn_mfma_f32_16x16x32_bf16(
                            af[tm], bf[tn], acc[tm][tn], 0, 0, 0);
            }
            __syncthreads();
        }
    }

    // ---- epilogue ----
    #pragma unroll
    for (int tm = 0; tm < 2; tm++) {
        int rbase = m0 + qm + tm * 16 + lg * 4;
        #pragma unroll
        for (int reg = 0; reg < 4; reg++) {
            int row = rbase + reg;
            if (row >= NN) continue;
            #pragma unroll
            for (int tn = 0; tn < TNW; tn++) {
                int col = qn + tn * 16 + lr;
                float v = acc[tm][tn][reg] + bias[col];
                if (ALAYER) {
                    v = fmaxf(v, 0.f);
                    ((unsigned short*)out)[(size_t)row * 256 + col] = f2bf(v);
                } else {
                    ((float*)out)[(size_t)row * 256 + col] = v;
                }
            }
        }
    }
}

// ---------------- AB = feat @ Mcat  [N x 16] (float4 loads) ----------------
__global__ void k_ab(const float* __restrict__ feat, const float* __restrict__ Mcat,
                     float* __restrict__ AB) {
    __shared__ float Ms[4096];
    int t = threadIdx.x;
    for (int i = t; i < 4096; i += 256) Ms[i] = Mcat[i];
    __syncthreads();
    int n = blockIdx.x * 16 + (t >> 4);
    int c = t & 15;
    const float4* fr = (const float4*)(feat + (size_t)n * 256);
    float s = 0.f;
    #pragma unroll 8
    for (int k4 = 0; k4 < 64; k4++) {
        float4 v = fr[k4];
        s += v.x * Ms[(k4 * 4 + 0) * 16 + c] + v.y * Ms[(k4 * 4 + 1) * 16 + c]
           + v.z * Ms[(k4 * 4 + 2) * 16 + c] + v.w * Ms[(k4 * 4 + 3) * 16 + c];
    }
    AB[(size_t)n * 16 + c] = s;
}

// ---------------- per-edge decoder ----------------
__global__ void k_dec(const int* __restrict__ dsrc, const int* __restrict__ ddst,
                      const float* __restrict__ AB, const float* __restrict__ cvec,
                      float* __restrict__ out) {
    int i = blockIdx.x * blockDim.x + threadIdx.x;
    if (i >= EDD * 8) return;
    int e = i >> 3, k = i & 7;
    out[i] = AB[dsrc[e] * 16 + k] + AB[ddst[e] * 16 + 8 + k] + cvec[k];
}

extern "C" void kernel_launch(void* const* d_in, const int* in_sizes, int n_in,
                              void* d_out, int out_size, void* d_ws, size_t ws_size,
                              hipStream_t stream) {
    const float* x2  = (const float*)d_in[0];
    const float* x3  = (const float*)d_in[1];
    const int*   src = (const int*)d_in[2];
    const int*   dst = (const int*)d_in[3];
    const int*   dsrc = (const int*)d_in[4];
    const int*   ddst = (const int*)d_in[5];
    const float* W2a = (const float*)d_in[6];
    const float* b2a = (const float*)d_in[7];
    const float* W2b = (const float*)d_in[8];
    const float* b2b = (const float*)d_in[9];
    const float* W3a = (const float*)d_in[10];
    const float* b3a = (const float*)d_in[11];
    const float* W3b = (const float*)d_in[12];
    const float* b3b = (const float*)d_in[13];
    const float* Wp1 = (const float*)d_in[14];
    const float* bp1 = (const float*)d_in[15];
    const float* Wp2 = (const float*)d_in[16];
    const float* bp2 = (const float*)d_in[17];
    float* out = (float*)d_out;

    // ---- workspace layout (~132 MB; Y intermediate eliminated) ----
    char* ws = (char*)d_ws;
    size_t off = 0;
    auto alloc = [&](size_t nbytes) {
        char* p = ws + off;
        off += nbytes;
        off = (off + 255) & ~(size_t)255;
        return p;
    };
    float* ns   = (float*)alloc((size_t)RR * NN * 4);        // aliases outdeg
    float* nd   = (float*)alloc((size_t)RR * NN * 4);        // aliases indeg
    int*   offs = (int*)alloc((size_t)RR * (NN + 1) * 4);
    int2*  csrw = (int2*)alloc((size_t)RR * EE * 8);
    unsigned short* XH   = (unsigned short*)alloc((size_t)NN * 320 * 2);  // x2b (256-stride) then x3b (320-stride)
    unsigned short* hbuf = (unsigned short*)alloc((size_t)NN * 256 * 2);  // layer-a out; AB aliases
    unsigned short* WT2a = (unsigned short*)alloc((size_t)256 * 2048 * 2);
    unsigned short* WT2b = (unsigned short*)alloc((size_t)128 * 2048 * 2);
    unsigned short* WT3a = (unsigned short*)alloc((size_t)256 * 2560 * 2);
    unsigned short* WT3b = (unsigned short*)alloc((size_t)128 * 2048 * 2);
    float* feat  = (float*)alloc((size_t)NN * 256 * 4);
    float* bsums = (float*)alloc(1024 * 4);
    float* Mcat  = (float*)alloc(4096 * 4);
    float* cvec  = (float*)alloc(64 * 4);
    int*   bsum  = (int*)alloc((size_t)RR * SCB * 4);
    int*   cursor = (int*)alloc((size_t)RR * NN * 4);

    int*   outdeg = (int*)ns;
    int*   indeg  = (int*)nd;
    float* AB     = (float*)hbuf;  // only live after last hbuf read

    // ---- graph prep ----
    hipMemsetAsync(outdeg, 0, (size_t)RR * NN * 4, stream);
    hipMemsetAsync(indeg,  0, (size_t)RR * NN * 4, stream);
    hipMemsetAsync(cursor, 0, (size_t)RR * NN * 4, stream);

    int edgeBlocks = (RR * EE + 255) / 256;
    k_hist<<<edgeBlocks, 256, 0, stream>>>(src, dst, outdeg, indeg);
    k_scanA<<<dim3(SCB, RR), 256, 0, stream>>>(indeg, bsum);
    k_scanB<<<RR, 256, 0, stream>>>(bsum, offs);
    k_scanC<<<dim3(SCB, RR), 256, 0, stream>>>(indeg, bsum, offs);
    k_norms<<<(RR * NN + 255) / 256, 256, 0, stream>>>(outdeg, indeg);
    k_fillw<<<edgeBlocks, 256, 0, stream>>>(src, dst, offs, ns, cursor, csrw);
    k_prep<<<18, 256, 0, stream>>>(Wp1, Wp2, bp1, bp2, b2a, b2b, b3a, b3b, Mcat, cvec, bsums);

    k_cast<<<(NN * 256 + 255) / 256, 256, 0, stream>>>(x2, XH, NN * 256);
    k_wt4<<<dim3(2560, 4), 256, 0, stream>>>(W2a, W2b, W3a, W3b, WT2a, WT2b, WT3a, WT3b);

    const int GB = (NN + 63) / 64;   // 782 blocks

    // ---- layer 2a: hbuf = relu(sum_r agg_r(x2b) @ W2a_r + b2a_sum) ----
    k_fused<256, true><<<GB, 256, 0, stream>>>(XH, 256, 256, WT2a, 2048, bsums + 0,
                                               csrw, offs, nd, (void*)hbuf);
    // ---- layer 2b: feat[:, :128] = sum_r agg_r(hbuf) @ W2b_r + b2b_sum ----
    k_fused<128, false><<<GB, 256, 0, stream>>>(hbuf, 256, 256, WT2b, 2048, bsums + 256,
                                                csrw, offs, nd, (void*)feat);
    // ---- layer 3a (x3: din 300 padded to 320) ----
    k_cast_pad<<<(NN * 320 + 255) / 256, 256, 0, stream>>>(x3, XH);
    k_fused<256, true><<<GB, 256, 0, stream>>>(XH, 320, 320, WT3a, 2560, bsums + 512,
                                               csrw, offs, nd, (void*)hbuf);
    // ---- layer 3b: feat[:, 128:] ----
    k_fused<128, false><<<GB, 256, 0, stream>>>(hbuf, 256, 256, WT3b, 2048, bsums + 768,
                                                csrw, offs, nd, (void*)(feat + 128));

    // ---- decoder ----
    k_ab<<<NN / 16, 256, 0, stream>>>(feat, Mcat, AB);
    k_dec<<<(EDD * 8 + 255) / 256, 256, 0, stream>>>(dsrc, ddst, AB, cvec, out);
}

// Round 3
// 1260.518 us; speedup vs baseline: 1.6893x; 1.6893x over previous
//
#include <hip/hip_runtime.h>
#include <hip/hip_bf16.h>

#define NN 50000
#define RR 8
#define EE 200000
#define EDD 400000
#define SCB 196   // ceil(NN/256) scan blocks
#define CH 5000   // phase-a node chunk (10 chunks)

typedef __attribute__((ext_vector_type(8))) short short8;
typedef __attribute__((ext_vector_type(4))) float floatx4;

static __device__ __forceinline__ unsigned short f2bf(float f) {
    union { float f; unsigned u; } v; v.f = f;
    unsigned r = v.u + 0x7fff + ((v.u >> 16) & 1);
    return (unsigned short)(r >> 16);
}
static __device__ __forceinline__ float bf2f(unsigned short h) {
    union { unsigned u; float f; } v; v.u = ((unsigned)h) << 16;
    return v.f;
}
// async global->LDS, 16B per lane; LDS dest = uniform base + lane*16
static __device__ __forceinline__ void gload_lds16(const unsigned short* g, unsigned short* l) {
    __builtin_amdgcn_global_load_lds(
        (const __attribute__((address_space(1))) void*)g,
        (__attribute__((address_space(3))) void*)l,
        16, 0, 0);
}

// ---------------- degree histogram: direct global atomics, full grid ----------------
__global__ void k_hist(const int* __restrict__ src, const int* __restrict__ dst,
                       int* __restrict__ outdeg, int* __restrict__ indeg) {
    int i = blockIdx.x * blockDim.x + threadIdx.x;
    if (i >= RR * EE) return;
    int r = i / EE;
    int base = r * NN;
    atomicAdd(&outdeg[base + src[i]], 1);
    atomicAdd(&indeg[base + dst[i]], 1);
}

// ---------------- norms: in-place int degree -> float rsqrt ----------------
__global__ void k_norms(int* __restrict__ outdeg, int* __restrict__ indeg) {
    int i = blockIdx.x * blockDim.x + threadIdx.x;
    if (i >= RR * NN) return;
    int od = outdeg[i];
    int id = indeg[i];
    ((float*)outdeg)[i] = od > 0 ? rsqrtf((float)od) : 0.f;
    ((float*)indeg)[i]  = id > 0 ? rsqrtf((float)id) : 0.f;
}

// ---------------- parallel scan: phase A (per-block sums) ----------------
__global__ void k_scanA(const int* __restrict__ indeg, int* __restrict__ bsum) {
    int r = blockIdx.y;
    int i = blockIdx.x * 256 + threadIdx.x;
    int v = (i < NN) ? indeg[(size_t)r * NN + i] : 0;
    #pragma unroll
    for (int d = 32; d > 0; d >>= 1) v += __shfl_down(v, d, 64);
    __shared__ int ws4[4];
    if ((threadIdx.x & 63) == 0) ws4[threadIdx.x >> 6] = v;
    __syncthreads();
    if (threadIdx.x == 0) bsum[r * SCB + blockIdx.x] = ws4[0] + ws4[1] + ws4[2] + ws4[3];
}

// ---------------- phase B: exclusive scan of SCB block sums per relation ----------------
__global__ void k_scanB(int* __restrict__ bsum, int* __restrict__ offs) {
    int r = blockIdx.x;
    int t = threadIdx.x;
    int v = (t < SCB) ? bsum[r * SCB + t] : 0;
    int lane = t & 63, wid = t >> 6;
    int sv = v;
    #pragma unroll
    for (int d = 1; d < 64; d <<= 1) {
        int u = __shfl_up(sv, d, 64);
        if (lane >= d) sv += u;
    }
    __shared__ int wsum[4];
    if (lane == 63) wsum[wid] = sv;
    __syncthreads();
    int add = 0;
    for (int x = 0; x < wid; x++) add += wsum[x];
    int incl = sv + add;
    if (t < SCB) bsum[r * SCB + t] = incl - v;
    if (t == 255) offs[(size_t)r * (NN + 1) + NN] = incl;  // grand total
}

// ---------------- phase C: intra-block exclusive scan + base ----------------
__global__ void k_scanC(const int* __restrict__ indeg, const int* __restrict__ bsum,
                        int* __restrict__ offs) {
    int r = blockIdx.y;
    int i = blockIdx.x * 256 + threadIdx.x;
    int v = (i < NN) ? indeg[(size_t)r * NN + i] : 0;
    int lane = threadIdx.x & 63, wid = threadIdx.x >> 6;
    int sv = v;
    #pragma unroll
    for (int d = 1; d < 64; d <<= 1) {
        int u = __shfl_up(sv, d, 64);
        if (lane >= d) sv += u;
    }
    __shared__ int wsum[4];
    if (lane == 63) wsum[wid] = sv;
    __syncthreads();
    int add = bsum[r * SCB + blockIdx.x];
    for (int x = 0; x < wid; x++) add += wsum[x];
    if (i < NN) offs[(size_t)r * (NN + 1) + i] = sv - v + add;
}

// ---------------- fill CSR with fused src-norm weight: (src, ns[r][src]) ----------------
__global__ void k_fillw(const int* __restrict__ src, const int* __restrict__ dst,
                        const int* __restrict__ offs, const float* __restrict__ ns,
                        int* __restrict__ cursor, int2* __restrict__ csrw) {
    int i = blockIdx.x * blockDim.x + threadIdx.x;
    if (i >= RR * EE) return;
    int r = i / EE;
    int s = src[i], d = dst[i];
    int pos = offs[r * (NN + 1) + d] + atomicAdd(&cursor[r * NN + d], 1);
    int2 v;
    v.x = s;
    v.y = __float_as_int(ns[(size_t)r * NN + s]);
    csrw[(size_t)r * EE + pos] = v;
}

// ---------------- decoder prep (Mcat, cvec) + bias sums, one launch ----------------
__global__ void k_prep(const float* __restrict__ Wp1, const float* __restrict__ Wp2,
                       const float* __restrict__ bp1, const float* __restrict__ bp2,
                       const float* __restrict__ b2a, const float* __restrict__ b2b,
                       const float* __restrict__ b3a, const float* __restrict__ b3b,
                       float* __restrict__ Mcat, float* __restrict__ cvec,
                       float* __restrict__ bs) {
    int bx = blockIdx.x;
    if (bx < 16) {
        int t = bx * 256 + threadIdx.x;      // 4096 elements
        int i = t >> 4, j = t & 15;
        int half = j >> 3, jj = j & 7;
        const float* wrow = Wp1 + (size_t)(half * 256 + i) * 256;
        float s = 0.f;
        for (int k = 0; k < 256; k++) s += wrow[k] * Wp2[k * 8 + jj];
        Mcat[i * 16 + j] = s;
    } else if (bx == 16) {
        int j = threadIdx.x;
        if (j < 8) {
            float s = bp2[j];
            for (int k = 0; k < 256; k++) s += bp1[k] * Wp2[k * 8 + j];
            cvec[j] = s;
        }
    } else {
        int j = threadIdx.x;  // 256
        float s = 0.f;
        for (int r = 0; r < RR; r++) s += b2a[r * 256 + j];
        bs[j] = s;
        if (j < 128) {
            s = 0.f;
            for (int r = 0; r < RR; r++) s += b2b[r * 128 + j];
            bs[256 + j] = s;
        }
        s = 0.f;
        for (int r = 0; r < RR; r++) s += b3a[r * 256 + j];
        bs[512 + j] = s;
        if (j < 128) {
            s = 0.f;
            for (int r = 0; r < RR; r++) s += b3b[r * 128 + j];
            bs[768 + j] = s;
        }
    }
}

// ---------------- fold b-layer weights through decoder: FmatT[128][512] bf16, cfold[16] ----
// F_r[k<256, j] = sum_i W2b[r][k][i] * Mcat[i][j];  F_r[256+k, j] = sum_i W3b[r][k][i]*Mcat[128+i][j]
// FmatT[(r*16+j)][k] = F_r[k][j]   (row-contiguous for GEMM BT)
__global__ void k_fold(const float* __restrict__ W2b, const float* __restrict__ W3b,
                       const float* __restrict__ Mcat, const float* __restrict__ bs,
                       unsigned short* __restrict__ FmatT, float* __restrict__ cfold) {
    int bx = blockIdx.x;
    if (bx < 256) {
        int idx = bx * 256 + threadIdx.x;      // 65536 = 128 rows x 512 cols
        int rj = idx >> 9, i = idx & 511;
        int r = rj >> 4, j = rj & 15;
        float s = 0.f;
        if (i < 256) {
            const float* wr = W2b + ((size_t)r * 256 + i) * 128;
            for (int c = 0; c < 128; c++) s += wr[c] * Mcat[c * 16 + j];
        } else {
            const float* wr = W3b + ((size_t)r * 256 + (i - 256)) * 128;
            for (int c = 0; c < 128; c++) s += wr[c] * Mcat[(128 + c) * 16 + j];
        }
        FmatT[(size_t)rj * 512 + i] = f2bf(s);
    } else {
        int j = threadIdx.x;
        if (j < 16) {
            float s = 0.f;
            for (int c = 0; c < 128; c++)
                s += bs[256 + c] * Mcat[c * 16 + j] + bs[768 + c] * Mcat[(128 + c) * 16 + j];
            cfold[j] = s;
        }
    }
}

// ---------------- interleaved bf16 cast: XH[m] = [x2(256) | x3(300) | 0 x4], stride 560 ----
__global__ void k_castx(const float* __restrict__ x2, const float* __restrict__ x3,
                        unsigned short* __restrict__ XH) {
    int i = blockIdx.x * 256 + threadIdx.x;
    if (i >= NN * 560) return;
    int row = i / 560, col = i - row * 560;
    float v;
    if (col < 256) v = x2[(size_t)row * 256 + col];
    else if (col < 556) v = x3[(size_t)row * 300 + (col - 256)];
    else v = 0.f;
    XH[i] = f2bf(v);
}

// ---------------- weight transposes (a-layers only): WT[n][r][kpad] bf16 ----------------
__global__ void k_wt2(const float* __restrict__ W2a, const float* __restrict__ W3a,
                      unsigned short* __restrict__ WT2, unsigned short* __restrict__ WT3) {
    const float* W; unsigned short* WT; int K0, Kpad;
    if (blockIdx.y == 0) { W = W2a; WT = WT2; K0 = 256; Kpad = 256; }
    else                 { W = W3a; WT = WT3; K0 = 300; Kpad = 304; }
    int i = blockIdx.x * 256 + threadIdx.x;
    int total = 256 * RR * Kpad;
    if (i >= total) return;
    int n = i / (RR * Kpad);
    int rem = i - n * (RR * Kpad);
    int r = rem / Kpad;
    int k = rem - r * Kpad;
    float v = (k < K0) ? W[((size_t)r * K0 + k) * 256 + n] : 0.f;
    WT[i] = f2bf(v);
}

// ---------------- dual-payload aggregation: wave per (node, relation), no LDS ----------------
// Gathers x2-part (256 cols) and x3-part (304 cols) of the interleaved XH row per edge.
// 8-12 loads in flight per 4-edge unroll -> latency-tolerant.
__global__ __launch_bounds__(256) void k_aggp(
        const unsigned short* __restrict__ xb,
        const int2* __restrict__ csrw, const int* __restrict__ offs,
        const float* __restrict__ nd, int nbase,
        unsigned short* __restrict__ Y2, unsigned short* __restrict__ Y3) {
    int lane = threadIdx.x & 63;
    int sub = threadIdx.x >> 6;
    int bn = blockIdx.x * 4 + sub;
    int n = nbase + bn;
    int r = blockIdx.y;
    int o0 = offs[r * (NN + 1) + n];
    int o1 = offs[r * (NN + 1) + n + 1];
    o0 = __builtin_amdgcn_readfirstlane(o0);
    o1 = __builtin_amdgcn_readfirstlane(o1);
    float ndv = nd[(size_t)r * NN + n];
    const int2* cs = csrw + (size_t)r * EE;
    bool ex = lane < 12;                 // x3 cols 256..303
    float pa[4], qa[4], xa[4];
    #pragma unroll
    for (int q = 0; q < 4; q++) { pa[q] = 0.f; qa[q] = 0.f; xa[q] = 0.f; }
    int e = o0;
    for (; e + 4 <= o1; e += 4) {
        int2 w0 = cs[e], w1 = cs[e + 1], w2 = cs[e + 2], w3 = cs[e + 3];
        const unsigned short* p0 = xb + (size_t)(unsigned)w0.x * 560;
        const unsigned short* p1 = xb + (size_t)(unsigned)w1.x * 560;
        const unsigned short* p2 = xb + (size_t)(unsigned)w2.x * 560;
        const unsigned short* p3 = xb + (size_t)(unsigned)w3.x * 560;
        ushort4 a0 = *(const ushort4*)(p0 + lane * 4);
        ushort4 a1 = *(const ushort4*)(p1 + lane * 4);
        ushort4 a2 = *(const ushort4*)(p2 + lane * 4);
        ushort4 a3 = *(const ushort4*)(p3 + lane * 4);
        ushort4 b0 = *(const ushort4*)(p0 + 256 + lane * 4);
        ushort4 b1 = *(const ushort4*)(p1 + 256 + lane * 4);
        ushort4 b2 = *(const ushort4*)(p2 + 256 + lane * 4);
        ushort4 b3 = *(const ushort4*)(p3 + 256 + lane * 4);
        float f0 = __int_as_float(w0.y), f1 = __int_as_float(w1.y);
        float f2 = __int_as_float(w2.y), f3 = __int_as_float(w3.y);
        pa[0] += f0 * bf2f(a0.x) + f1 * bf2f(a1.x) + f2 * bf2f(a2.x) + f3 * bf2f(a3.x);
        pa[1] += f0 * bf2f(a0.y) + f1 * bf2f(a1.y) + f2 * bf2f(a2.y) + f3 * bf2f(a3.y);
        pa[2] += f0 * bf2f(a0.z) + f1 * bf2f(a1.z) + f2 * bf2f(a2.z) + f3 * bf2f(a3.z);
        pa[3] += f0 * bf2f(a0.w) + f1 * bf2f(a1.w) + f2 * bf2f(a2.w) + f3 * bf2f(a3.w);
        qa[0] += f0 * bf2f(b0.x) + f1 * bf2f(b1.x) + f2 * bf2f(b2.x) + f3 * bf2f(b3.x);
        qa[1] += f0 * bf2f(b0.y) + f1 * bf2f(b1.y) + f2 * bf2f(b2.y) + f3 * bf2f(b3.y);
        qa[2] += f0 * bf2f(b0.z) + f1 * bf2f(b1.z) + f2 * bf2f(b2.z) + f3 * bf2f(b3.z);
        qa[3] += f0 * bf2f(b0.w) + f1 * bf2f(b1.w) + f2 * bf2f(b2.w) + f3 * bf2f(b3.w);
        if (ex) {
            ushort4 c0 = *(const ushort4*)(p0 + 512 + lane * 4);
            ushort4 c1 = *(const ushort4*)(p1 + 512 + lane * 4);
            ushort4 c2 = *(const ushort4*)(p2 + 512 + lane * 4);
            ushort4 c3 = *(const ushort4*)(p3 + 512 + lane * 4);
            xa[0] += f0 * bf2f(c0.x) + f1 * bf2f(c1.x) + f2 * bf2f(c2.x) + f3 * bf2f(c3.x);
            xa[1] += f0 * bf2f(c0.y) + f1 * bf2f(c1.y) + f2 * bf2f(c2.y) + f3 * bf2f(c3.y);
            xa[2] += f0 * bf2f(c0.z) + f1 * bf2f(c1.z) + f2 * bf2f(c2.z) + f3 * bf2f(c3.z);
            xa[3] += f0 * bf2f(c0.w) + f1 * bf2f(c1.w) + f2 * bf2f(c2.w) + f3 * bf2f(c3.w);
        }
    }
    for (; e < o1; e++) {
        int2 w0 = cs[e];
        const unsigned short* p0 = xb + (size_t)(unsigned)w0.x * 560;
        ushort4 a0 = *(const ushort4*)(p0 + lane * 4);
        ushort4 b0 = *(const ushort4*)(p0 + 256 + lane * 4);
        float f0 = __int_as_float(w0.y);
        pa[0] += f0 * bf2f(a0.x); pa[1] += f0 * bf2f(a0.y);
        pa[2] += f0 * bf2f(a0.z); pa[3] += f0 * bf2f(a0.w);
        qa[0] += f0 * bf2f(b0.x); qa[1] += f0 * bf2f(b0.y);
        qa[2] += f0 * bf2f(b0.z); qa[3] += f0 * bf2f(b0.w);
        if (ex) {
            ushort4 c0 = *(const ushort4*)(p0 + 512 + lane * 4);
            xa[0] += f0 * bf2f(c0.x); xa[1] += f0 * bf2f(c0.y);
            xa[2] += f0 * bf2f(c0.z); xa[3] += f0 * bf2f(c0.w);
        }
    }
    ushort4 op, oq;
    op.x = f2bf(pa[0] * ndv); op.y = f2bf(pa[1] * ndv);
    op.z = f2bf(pa[2] * ndv); op.w = f2bf(pa[3] * ndv);
    oq.x = f2bf(qa[0] * ndv); oq.y = f2bf(qa[1] * ndv);
    oq.z = f2bf(qa[2] * ndv); oq.w = f2bf(qa[3] * ndv);
    *(ushort4*)(Y2 + (size_t)bn * 2048 + r * 256 + lane * 4) = op;
    *(ushort4*)(Y3 + (size_t)bn * 2432 + r * 304 + lane * 4) = oq;
    if (ex) {
        ushort4 ox;
        ox.x = f2bf(xa[0] * ndv); ox.y = f2bf(xa[1] * ndv);
        ox.z = f2bf(xa[2] * ndv); ox.w = f2bf(xa[3] * ndv);
        *(ushort4*)(Y3 + (size_t)bn * 2432 + r * 304 + 256 + lane * 4) = ox;
    }
}

// ---------------- generic bf16 MFMA GEMM (r0-proven), used for G projection ----------------
// flags: 1=addbias, 2=accum(read Cin fp32), 4=relu, 8=out bf16 (else fp32)
template<int TN>
__global__ __launch_bounds__(256) void k_gemm_bf(
        const unsigned short* __restrict__ A, int lda,
        const unsigned short* __restrict__ BT, int ldb,
        const float* __restrict__ bias,
        const float* __restrict__ Cin, int ldcin,
        void* __restrict__ Cout, int ldc,
        int M, int K, int flags) {
    constexpr int BN = TN * 32;
    __shared__ unsigned short As[128 * 64];
    __shared__ unsigned short Bs[BN * 64];
    int m0 = blockIdx.x * 128;
    int n0 = blockIdx.y * BN;
    int t = threadIdx.x;
    int w = t >> 6, l = t & 63;
    int qm = (w >> 1) * 64, qn = (w & 1) * (TN * 16);
    int lr = l & 15, lg = l >> 4;
    int lrow = l >> 3;
    int lch  = (l & 7) ^ lrow;

    floatx4 acc[4][TN];
    #pragma unroll
    for (int a = 0; a < 4; a++)
        #pragma unroll
        for (int b = 0; b < TN; b++)
            acc[a][b] = (floatx4){0.f, 0.f, 0.f, 0.f};

    for (int k0 = 0; k0 < K; k0 += 64) {
        #pragma unroll
        for (int j = 0; j < 4; j++) {
            int seg = w * 4 + j;
            int gr = m0 + seg * 8 + lrow; if (gr > M - 1) gr = M - 1;
            gload_lds16(A + (size_t)gr * lda + k0 + lch * 8, &As[seg * 512]);
        }
        #pragma unroll
        for (int j = 0; j < TN; j++) {
            int seg = w * TN + j;
            int row = n0 + seg * 8 + lrow;
            gload_lds16(BT + (size_t)row * ldb + k0 + lch * 8, &Bs[seg * 512]);
        }
        __syncthreads();
        #pragma unroll
        for (int ks = 0; ks < 2; ks++) {
            int slot = ((ks * 4 + lg) ^ (lr & 7)) * 8;
            short8 af[4], bf[TN];
            #pragma unroll
            for (int i = 0; i < 4; i++)
                af[i] = *(const short8*)&As[(qm + i * 16 + lr) * 64 + slot];
            #pragma unroll
            for (int i = 0; i < TN; i++)
                bf[i] = *(const short8*)&Bs[(qn + i * 16 + lr) * 64 + slot];
            #pragma unroll
            for (int tm = 0; tm < 4; tm++)
                #pragma unroll
                for (int tn = 0; tn < TN; tn++)
                    acc[tm][tn] = __builtin_amdgcn_mfma_f32_16x16x32_bf16(
                        af[tm], bf[tn], acc[tm][tn], 0, 0, 0);
        }
        __syncthreads();
    }

    int addbias = flags & 1, accum = flags & 2, relu = flags & 4, outbf = flags & 8;
    #pragma unroll
    for (int tm = 0; tm < 4; tm++) {
        int rbase = m0 + qm + tm * 16 + lg * 4;
        #pragma unroll
        for (int reg = 0; reg < 4; reg++) {
            int row = rbase + reg;
            if (row >= M) continue;
            #pragma unroll
            for (int tn = 0; tn < TN; tn++) {
                int col = n0 + qn + tn * 16 + lr;
                float v = acc[tm][tn][reg];
                if (addbias) v += bias[col];
                if (accum) v += Cin[(size_t)row * ldcin + col];
                if (relu) v = fmaxf(v, 0.f);
                if (outbf) ((unsigned short*)Cout)[(size_t)row * ldc + col] = f2bf(v);
                else       ((float*)Cout)[(size_t)row * ldc + col] = v;
            }
        }
    }
}

// ---------------- paired a-layer GEMM: z=0 -> 2a (K=2048), z=1 -> 3a (K=2432) ----------------
// out: hbuf23[(nbase+row)*512 + z*256 + col] = relu(acc + bias)  bf16
__global__ __launch_bounds__(256) void k_gemm2(
        const unsigned short* __restrict__ Y2, const unsigned short* __restrict__ Y3,
        const unsigned short* __restrict__ WT2, const unsigned short* __restrict__ WT3,
        const float* __restrict__ bs, unsigned short* __restrict__ hb,
        int nbase, int M) {
    constexpr int TN = 2;
    __shared__ unsigned short As[128 * 64];
    __shared__ unsigned short Bs[64 * 64];
    int z = blockIdx.z;
    const unsigned short* A  = z ? Y3 : Y2;
    const unsigned short* BT = z ? WT3 : WT2;
    int lda = z ? 2432 : 2048;
    int K = lda;
    const float* bias = bs + z * 512;
    int m0 = blockIdx.x * 128;
    int n0 = blockIdx.y * 64;
    int t = threadIdx.x;
    int w = t >> 6, l = t & 63;
    int qm = (w >> 1) * 64, qn = (w & 1) * 32;
    int lr = l & 15, lg = l >> 4;
    int lrow = l >> 3;
    int lch  = (l & 7) ^ lrow;

    floatx4 acc[4][TN];
    #pragma unroll
    for (int a = 0; a < 4; a++)
        #pragma unroll
        for (int b = 0; b < TN; b++)
            acc[a][b] = (floatx4){0.f, 0.f, 0.f, 0.f};

    for (int k0 = 0; k0 < K; k0 += 64) {
        #pragma unroll
        for (int j = 0; j < 4; j++) {
            int seg = w * 4 + j;
            int gr = m0 + seg * 8 + lrow; if (gr > M - 1) gr = M - 1;
            gload_lds16(A + (size_t)gr * lda + k0 + lch * 8, &As[seg * 512]);
        }
        #pragma unroll
        for (int j = 0; j < TN; j++) {
            int seg = w * TN + j;
            int row = n0 + seg * 8 + lrow;
            gload_lds16(BT + (size_t)row * lda + k0 + lch * 8, &Bs[seg * 512]);
        }
        __syncthreads();
        #pragma unroll
        for (int ks = 0; ks < 2; ks++) {
            int slot = ((ks * 4 + lg) ^ (lr & 7)) * 8;
            short8 af[4], bf[TN];
            #pragma unroll
            for (int i = 0; i < 4; i++)
                af[i] = *(const short8*)&As[(qm + i * 16 + lr) * 64 + slot];
            #pragma unroll
            for (int i = 0; i < TN; i++)
                bf[i] = *(const short8*)&Bs[(qn + i * 16 + lr) * 64 + slot];
            #pragma unroll
            for (int tm = 0; tm < 4; tm++)
                #pragma unroll
                for (int tn = 0; tn < TN; tn++)
                    acc[tm][tn] = __builtin_amdgcn_mfma_f32_16x16x32_bf16(
                        af[tm], bf[tn], acc[tm][tn], 0, 0, 0);
        }
        __syncthreads();
    }

    #pragma unroll
    for (int tm = 0; tm < 4; tm++) {
        int rbase = m0 + qm + tm * 16 + lg * 4;
        #pragma unroll
        for (int reg = 0; reg < 4; reg++) {
            int row = rbase + reg;
            if (row >= M) continue;
            #pragma unroll
            for (int tn = 0; tn < TN; tn++) {
                int col = n0 + qn + tn * 16 + lr;
                float v = fmaxf(acc[tm][tn][reg] + bias[col], 0.f);
                hb[(size_t)(nbase + row) * 512 + z * 256 + col] = f2bf(v);
            }
        }
    }
}

// ---------------- 16-dim projected aggregation: AB[n, 0:16] ----------------
// AB[n,j] = cfold[j] + sum_r nd_r[n] * sum_e ns_e * G[src_e * 128 + r*16 + j]
__global__ __launch_bounds__(256) void k_aggAB(
        const int2* __restrict__ csrw, const int* __restrict__ offs,
        const float* __restrict__ nd, const float* __restrict__ G,
        const float* __restrict__ cfold, float* __restrict__ AB) {
    int lane = threadIdx.x & 63, sub = threadIdx.x >> 6;
    int n = blockIdx.x * 4 + sub;
    int slot = lane >> 4, j = lane & 15;
    float acc = 0.f;
    for (int r = 0; r < RR; r++) {
        int o0 = offs[r * (NN + 1) + n];
        int o1 = offs[r * (NN + 1) + n + 1];
        o0 = __builtin_amdgcn_readfirstlane(o0);
        o1 = __builtin_amdgcn_readfirstlane(o1);
        float ndv = nd[(size_t)r * NN + n];
        const int2* cs = csrw + (size_t)r * EE;
        float tr = 0.f;
        for (int e = o0 + slot; e < o1; e += 4) {
            int2 w = cs[e];
            tr += __int_as_float(w.y) * G[(size_t)(unsigned)w.x * 128 + r * 16 + j];
        }
        acc += ndv * tr;
    }
    acc += __shfl_xor(acc, 16, 64);
    acc += __shfl_xor(acc, 32, 64);
    if (lane < 16) AB[(size_t)n * 16 + j] = acc + cfold[j];
}

// ---------------- per-edge decoder ----------------
__global__ void k_dec(const int* __restrict__ dsrc, const int* __restrict__ ddst,
                      const float* __restrict__ AB, const float* __restrict__ cvec,
                      float* __restrict__ out) {
    int i = blockIdx.x * blockDim.x + threadIdx.x;
    if (i >= EDD * 8) return;
    int e = i >> 3, k = i & 7;
    out[i] = AB[dsrc[e] * 16 + k] + AB[ddst[e] * 16 + 8 + k] + cvec[k];
}

extern "C" void kernel_launch(void* const* d_in, const int* in_sizes, int n_in,
                              void* d_out, int out_size, void* d_ws, size_t ws_size,
                              hipStream_t stream) {
    const float* x2  = (const float*)d_in[0];
    const float* x3  = (const float*)d_in[1];
    const int*   src = (const int*)d_in[2];
    const int*   dst = (const int*)d_in[3];
    const int*   dsrc = (const int*)d_in[4];
    const int*   ddst = (const int*)d_in[5];
    const float* W2a = (const float*)d_in[6];
    const float* b2a = (const float*)d_in[7];
    const float* W2b = (const float*)d_in[8];
    const float* b2b = (const float*)d_in[9];
    const float* W3a = (const float*)d_in[10];
    const float* b3a = (const float*)d_in[11];
    const float* W3b = (const float*)d_in[12];
    const float* b3b = (const float*)d_in[13];
    const float* Wp1 = (const float*)d_in[14];
    const float* bp1 = (const float*)d_in[15];
    const float* Wp2 = (const float*)d_in[16];
    const float* bp2 = (const float*)d_in[17];
    float* out = (float*)d_out;

    // ---- workspace layout (~172 MB < proven 182.4 MB bound) ----
    char* ws = (char*)d_ws;
    size_t off = 0;
    auto alloc = [&](size_t nbytes) {
        char* p = ws + off;
        off += nbytes;
        off = (off + 255) & ~(size_t)255;
        return p;
    };
    float* ns   = (float*)alloc((size_t)RR * NN * 4);        // aliases outdeg
    float* nd   = (float*)alloc((size_t)RR * NN * 4);        // aliases indeg
    int*   offs = (int*)alloc((size_t)RR * (NN + 1) * 4);
    int2*  csrw = (int2*)alloc((size_t)RR * EE * 8);
    unsigned short* XH     = (unsigned short*)alloc((size_t)NN * 560 * 2);  // [x2|x3|pad] interleaved
    unsigned short* hbuf23 = (unsigned short*)alloc((size_t)NN * 512 * 2);  // [h2a|h3a] interleaved
    unsigned short* WT2a   = (unsigned short*)alloc((size_t)256 * 2048 * 2);
    unsigned short* WT3a   = (unsigned short*)alloc((size_t)256 * 2432 * 2);
    unsigned short* FmatT  = (unsigned short*)alloc((size_t)128 * 512 * 2);
    char* YR = alloc((size_t)CH * (2048 + 2432) * 2);        // Y2a|Y3a; later G + AB
    float* Mcat  = (float*)alloc(4096 * 4);
    float* cvec  = (float*)alloc(64 * 4);
    float* bsums = (float*)alloc(1024 * 4);
    float* cfold = (float*)alloc(64 * 4);
    int*   bsum  = (int*)alloc((size_t)RR * SCB * 4);

    unsigned short* Y2a = (unsigned short*)YR;
    unsigned short* Y3a = Y2a + (size_t)CH * 2048;
    int*   outdeg = (int*)ns;
    int*   indeg  = (int*)nd;
    int*   cursor = (int*)YR;                 // live only during k_fillw
    float* G      = (float*)YR;               // [NN x 128] f32, live after phase a
    float* AB     = (float*)(YR + (size_t)NN * 128 * 4);  // 3.2 MB after G

    // ---- graph prep ----
    hipMemsetAsync(outdeg, 0, (size_t)RR * NN * 4, stream);
    hipMemsetAsync(indeg,  0, (size_t)RR * NN * 4, stream);
    hipMemsetAsync(cursor, 0, (size_t)RR * NN * 4, stream);

    int edgeBlocks = (RR * EE + 255) / 256;
    k_hist<<<edgeBlocks, 256, 0, stream>>>(src, dst, outdeg, indeg);
    k_scanA<<<dim3(SCB, RR), 256, 0, stream>>>(indeg, bsum);
    k_scanB<<<RR, 256, 0, stream>>>(bsum, offs);
    k_scanC<<<dim3(SCB, RR), 256, 0, stream>>>(indeg, bsum, offs);
    k_norms<<<(RR * NN + 255) / 256, 256, 0, stream>>>(outdeg, indeg);
    k_fillw<<<edgeBlocks, 256, 0, stream>>>(src, dst, offs, ns, cursor, csrw);
    k_prep<<<18, 256, 0, stream>>>(Wp1, Wp2, bp1, bp2, b2a, b2b, b3a, b3b, Mcat, cvec, bsums);
    k_fold<<<257, 256, 0, stream>>>(W2b, W3b, Mcat, bsums, FmatT, cfold);

    k_castx<<<(NN * 560 + 255) / 256, 256, 0, stream>>>(x2, x3, XH);
    k_wt2<<<dim3((256 * RR * 304 + 255) / 256, 2), 256, 0, stream>>>(W2a, W3a, WT2a, WT3a);

    // ---- phase a: chunked dual aggregation + paired GEMM -> hbuf23 (relu bf16) ----
    for (int c = 0; c < NN / CH; c++) {
        k_aggp<<<dim3(CH / 4, RR), 256, 0, stream>>>(XH, csrw, offs, nd, c * CH, Y2a, Y3a);
        k_gemm2<<<dim3((CH + 127) / 128, 4, 2), 256, 0, stream>>>(
            Y2a, Y3a, WT2a, WT3a, bsums, hbuf23, c * CH, CH);
    }

    // ---- phase b (folded): G = hbuf23 @ FmatT^T  [NN x 128] f32 ----
    k_gemm_bf<1><<<dim3((NN + 127) / 128, 4), 256, 0, stream>>>(
        hbuf23, 512, FmatT, 512, bsums, (const float*)nullptr, 0,
        (void*)G, 128, NN, 512, 0);

    // ---- projected aggregation -> AB, then decoder ----
    k_aggAB<<<NN / 4, 256, 0, stream>>>(csrw, offs, nd, G, cfold, AB);
    k_dec<<<(EDD * 8 + 255) / 256, 256, 0, stream>>>(dsrc, ddst, AB, cvec, out);
}

// Round 4
// 1195.411 us; speedup vs baseline: 1.7814x; 1.0545x over previous
//
#include <hip/hip_runtime.h>
#include <hip/hip_bf16.h>

#define NN 50000
#define RR 8
#define EE 200000
#define EDD 400000
#define SCB 196   // ceil(NN/256) scan blocks
#define CH 5000   // phase-a node chunk (10 chunks)
#define CHK 16    // histogram privatization chunks

typedef __attribute__((ext_vector_type(8))) short short8;
typedef __attribute__((ext_vector_type(4))) float floatx4;

static __device__ __forceinline__ unsigned short f2bf(float f) {
    union { float f; unsigned u; } v; v.f = f;
    unsigned r = v.u + 0x7fff + ((v.u >> 16) & 1);
    return (unsigned short)(r >> 16);
}
static __device__ __forceinline__ float bf2f(unsigned short h) {
    union { unsigned u; float f; } v; v.u = ((unsigned)h) << 16;
    return v.f;
}
// async global->LDS, 16B per lane; LDS dest = uniform base + lane*16
static __device__ __forceinline__ void gload_lds16(const unsigned short* g, unsigned short* l) {
    __builtin_amdgcn_global_load_lds(
        (const __attribute__((address_space(1))) void*)g,
        (__attribute__((address_space(3))) void*)l,
        16, 0, 0);
}

// ---------------- privatized degree histogram: 8-bit LDS bins, non-atomic flush ----------------
// grid (CHK, RR, 2 which). Each block: 12500 edges -> 50048-byte private copy (coalesced write).
// Replaces 3.2M global atomics (~100 MB HBM write amplification) with 12.8 MB linear writes.
__global__ __launch_bounds__(256) void k_histp(const int* __restrict__ src, const int* __restrict__ dst,
                                               unsigned char* __restrict__ tmp) {
    __shared__ unsigned lh[12512];   // 50048 bytes, 8-bit bins
    int chunk = blockIdx.x, r = blockIdx.y, which = blockIdx.z;
    const int* idx = (which ? dst : src) + (size_t)r * EE;
    for (int i = threadIdx.x; i < 12512; i += 256) lh[i] = 0;
    __syncthreads();
    int e0 = chunk * (EE / CHK);
    for (int e = e0 + threadIdx.x; e < e0 + EE / CHK; e += 256) {
        int n = idx[e];
        atomicAdd(&lh[n >> 2], 1u << ((n & 3) * 8));
    }
    __syncthreads();
    unsigned* t = (unsigned*)(tmp + (((size_t)(which * RR + r) * CHK + chunk) * 50048));
    for (int i = threadIdx.x; i < 12512; i += 256) t[i] = lh[i];
}

// ---------------- reduce the CHK private copies -> int degree arrays ----------------
__global__ void k_reduce(const unsigned char* __restrict__ tmp,
                         int* __restrict__ outdeg, int* __restrict__ indeg) {
    int i = blockIdx.x * 256 + threadIdx.x;
    if (i >= 2 * RR * 12512) return;
    int wr = i / 12512;        // which*RR + r
    int wd = i - wr * 12512;   // word index (4 nodes)
    unsigned s0 = 0, s1 = 0, s2 = 0, s3 = 0;
    const unsigned* base = (const unsigned*)(tmp + (size_t)wr * CHK * 50048) + wd;
    #pragma unroll
    for (int c = 0; c < CHK; c++) {
        unsigned v = base[(size_t)c * 12512];
        s0 += v & 255u; s1 += (v >> 8) & 255u; s2 += (v >> 16) & 255u; s3 += (v >> 24) & 255u;
    }
    int which = wr / RR, r = wr - which * RR;
    int n = wd * 4;
    int* deg = (which ? indeg : outdeg) + (size_t)r * NN;
    if (n < NN) {
        deg[n] = (int)s0;
        if (n + 1 < NN) deg[n + 1] = (int)s1;
        if (n + 2 < NN) deg[n + 2] = (int)s2;
        if (n + 3 < NN) deg[n + 3] = (int)s3;
    }
}

// ---------------- norms: in-place int degree -> float rsqrt ----------------
__global__ void k_norms(int* __restrict__ outdeg, int* __restrict__ indeg) {
    int i = blockIdx.x * blockDim.x + threadIdx.x;
    if (i >= RR * NN) return;
    int od = outdeg[i];
    int id = indeg[i];
    ((float*)outdeg)[i] = od > 0 ? rsqrtf((float)od) : 0.f;
    ((float*)indeg)[i]  = id > 0 ? rsqrtf((float)id) : 0.f;
}

// ---------------- parallel scan: phase A (per-block sums) ----------------
__global__ void k_scanA(const int* __restrict__ indeg, int* __restrict__ bsum) {
    int r = blockIdx.y;
    int i = blockIdx.x * 256 + threadIdx.x;
    int v = (i < NN) ? indeg[(size_t)r * NN + i] : 0;
    #pragma unroll
    for (int d = 32; d > 0; d >>= 1) v += __shfl_down(v, d, 64);
    __shared__ int ws4[4];
    if ((threadIdx.x & 63) == 0) ws4[threadIdx.x >> 6] = v;
    __syncthreads();
    if (threadIdx.x == 0) bsum[r * SCB + blockIdx.x] = ws4[0] + ws4[1] + ws4[2] + ws4[3];
}

// ---------------- phase B: exclusive scan of SCB block sums per relation ----------------
__global__ void k_scanB(int* __restrict__ bsum, int* __restrict__ offs) {
    int r = blockIdx.x;
    int t = threadIdx.x;
    int v = (t < SCB) ? bsum[r * SCB + t] : 0;
    int lane = t & 63, wid = t >> 6;
    int sv = v;
    #pragma unroll
    for (int d = 1; d < 64; d <<= 1) {
        int u = __shfl_up(sv, d, 64);
        if (lane >= d) sv += u;
    }
    __shared__ int wsum[4];
    if (lane == 63) wsum[wid] = sv;
    __syncthreads();
    int add = 0;
    for (int x = 0; x < wid; x++) add += wsum[x];
    int incl = sv + add;
    if (t < SCB) bsum[r * SCB + t] = incl - v;
    if (t == 255) offs[(size_t)r * (NN + 1) + NN] = incl;  // grand total
}

// ---------------- phase C: intra-block exclusive scan + base ----------------
__global__ void k_scanC(const int* __restrict__ indeg, const int* __restrict__ bsum,
                        int* __restrict__ offs) {
    int r = blockIdx.y;
    int i = blockIdx.x * 256 + threadIdx.x;
    int v = (i < NN) ? indeg[(size_t)r * NN + i] : 0;
    int lane = threadIdx.x & 63, wid = threadIdx.x >> 6;
    int sv = v;
    #pragma unroll
    for (int d = 1; d < 64; d <<= 1) {
        int u = __shfl_up(sv, d, 64);
        if (lane >= d) sv += u;
    }
    __shared__ int wsum[4];
    if (lane == 63) wsum[wid] = sv;
    __syncthreads();
    int add = bsum[r * SCB + blockIdx.x];
    for (int x = 0; x < wid; x++) add += wsum[x];
    if (i < NN) offs[(size_t)r * (NN + 1) + i] = sv - v + add;
}

// ---------------- fill CSR with fused src-norm weight: (src, ns[r][src]) ----------------
__global__ void k_fillw(const int* __restrict__ src, const int* __restrict__ dst,
                        const int* __restrict__ offs, const float* __restrict__ ns,
                        int* __restrict__ cursor, int2* __restrict__ csrw) {
    int i = blockIdx.x * blockDim.x + threadIdx.x;
    if (i >= RR * EE) return;
    int r = i / EE;
    int s = src[i], d = dst[i];
    int pos = offs[r * (NN + 1) + d] + atomicAdd(&cursor[r * NN + d], 1);
    int2 v;
    v.x = s;
    v.y = __float_as_int(ns[(size_t)r * NN + s]);
    csrw[(size_t)r * EE + pos] = v;
}

// ---------------- decoder prep (Mcat, cvec) + bias sums, one launch ----------------
__global__ void k_prep(const float* __restrict__ Wp1, const float* __restrict__ Wp2,
                       const float* __restrict__ bp1, const float* __restrict__ bp2,
                       const float* __restrict__ b2a, const float* __restrict__ b2b,
                       const float* __restrict__ b3a, const float* __restrict__ b3b,
                       float* __restrict__ Mcat, float* __restrict__ cvec,
                       float* __restrict__ bs) {
    int bx = blockIdx.x;
    if (bx < 16) {
        int t = bx * 256 + threadIdx.x;      // 4096 elements
        int i = t >> 4, j = t & 15;
        int half = j >> 3, jj = j & 7;
        const float* wrow = Wp1 + (size_t)(half * 256 + i) * 256;
        float s = 0.f;
        for (int k = 0; k < 256; k++) s += wrow[k] * Wp2[k * 8 + jj];
        Mcat[i * 16 + j] = s;
    } else if (bx == 16) {
        int j = threadIdx.x;
        if (j < 8) {
            float s = bp2[j];
            for (int k = 0; k < 256; k++) s += bp1[k] * Wp2[k * 8 + j];
            cvec[j] = s;
        }
    } else {
        int j = threadIdx.x;  // 256
        float s = 0.f;
        for (int r = 0; r < RR; r++) s += b2a[r * 256 + j];
        bs[j] = s;
        if (j < 128) {
            s = 0.f;
            for (int r = 0; r < RR; r++) s += b2b[r * 128 + j];
            bs[256 + j] = s;
        }
        s = 0.f;
        for (int r = 0; r < RR; r++) s += b3a[r * 256 + j];
        bs[512 + j] = s;
        if (j < 128) {
            s = 0.f;
            for (int r = 0; r < RR; r++) s += b3b[r * 128 + j];
            bs[768 + j] = s;
        }
    }
}

// ---------------- fold b-layer weights through decoder: FmatT[128][512] bf16, cfold[16] ----
__global__ void k_fold(const float* __restrict__ W2b, const float* __restrict__ W3b,
                       const float* __restrict__ Mcat, const float* __restrict__ bs,
                       unsigned short* __restrict__ FmatT, float* __restrict__ cfold) {
    int bx = blockIdx.x;
    if (bx < 256) {
        int idx = bx * 256 + threadIdx.x;      // 65536 = 128 rows x 512 cols
        int rj = idx >> 9, i = idx & 511;
        int r = rj >> 4, j = rj & 15;
        float s = 0.f;
        if (i < 256) {
            const float* wr = W2b + ((size_t)r * 256 + i) * 128;
            for (int c = 0; c < 128; c++) s += wr[c] * Mcat[c * 16 + j];
        } else {
            const float* wr = W3b + ((size_t)r * 256 + (i - 256)) * 128;
            for (int c = 0; c < 128; c++) s += wr[c] * Mcat[(128 + c) * 16 + j];
        }
        FmatT[(size_t)rj * 512 + i] = f2bf(s);
    } else {
        int j = threadIdx.x;
        if (j < 16) {
            float s = 0.f;
            for (int c = 0; c < 128; c++)
                s += bs[256 + c] * Mcat[c * 16 + j] + bs[768 + c] * Mcat[(128 + c) * 16 + j];
            cfold[j] = s;
        }
    }
}

// ---------------- interleaved bf16 cast: XH[m] = [x2(256) | x3(300) | 0 x4], stride 560 ----
__global__ void k_castx(const float* __restrict__ x2, const float* __restrict__ x3,
                        unsigned short* __restrict__ XH) {
    int i = blockIdx.x * 256 + threadIdx.x;
    if (i >= NN * 560) return;
    int row = i / 560, col = i - row * 560;
    float v;
    if (col < 256) v = x2[(size_t)row * 256 + col];
    else if (col < 556) v = x3[(size_t)row * 300 + (col - 256)];
    else v = 0.f;
    XH[i] = f2bf(v);
}

// ---------------- weight transposes (a-layers only): WT[n][r][kpad] bf16 ----------------
__global__ void k_wt2(const float* __restrict__ W2a, const float* __restrict__ W3a,
                      unsigned short* __restrict__ WT2, unsigned short* __restrict__ WT3) {
    const float* W; unsigned short* WT; int K0, Kpad;
    if (blockIdx.y == 0) { W = W2a; WT = WT2; K0 = 256; Kpad = 256; }
    else                 { W = W3a; WT = WT3; K0 = 300; Kpad = 304; }
    int i = blockIdx.x * 256 + threadIdx.x;
    int total = 256 * RR * Kpad;
    if (i >= total) return;
    int n = i / (RR * Kpad);
    int rem = i - n * (RR * Kpad);
    int r = rem / Kpad;
    int k = rem - r * Kpad;
    float v = (k < K0) ? W[((size_t)r * K0 + k) * 256 + n] : 0.f;
    WT[i] = f2bf(v);
}

// ---------------- dual-payload aggregation: wave per (node, relation), half-wave edges ----------
// lanes 0-31 process even edges, 32-63 odd edges; ushort8 (16B) loads cover each 512B segment.
// 8 edges in flight per unrolled iter -> ~2x per-wave MLP vs the 4-edge ushort4 version.
__global__ __launch_bounds__(256) void k_aggp(
        const unsigned short* __restrict__ xb,
        const int2* __restrict__ csrw, const int* __restrict__ offs,
        const float* __restrict__ nd, int nbase,
        unsigned short* __restrict__ Y2, unsigned short* __restrict__ Y3) {
    int lane = threadIdx.x & 63;
    int sub = threadIdx.x >> 6;
    int h = lane >> 5;           // half index (edge parity)
    int l = lane & 31;           // lane within half: col octet
    int bn = blockIdx.x * 4 + sub;
    int n = nbase + bn;
    int r = blockIdx.y;
    int o0 = offs[r * (NN + 1) + n];
    int o1 = offs[r * (NN + 1) + n + 1];
    o0 = __builtin_amdgcn_readfirstlane(o0);
    o1 = __builtin_amdgcn_readfirstlane(o1);
    float ndv = nd[(size_t)r * NN + n];
    const int2* cs = csrw + (size_t)r * EE;
    bool tl = l < 6;             // x3 tail cols 256..303 (+4 zero pad)
    float va[8], vb[8], vc[8];
    #pragma unroll
    for (int q = 0; q < 8; q++) { va[q] = 0.f; vb[q] = 0.f; vc[q] = 0.f; }
    int e = o0;
    for (; e + 8 <= o1; e += 8) {
        #pragma unroll
        for (int u = 0; u < 4; u++) {
            int2 w = cs[e + 2 * u + h];
            const unsigned short* p = xb + (size_t)(unsigned)w.x * 560;
            short8 A = *(const short8*)(p + l * 8);
            short8 B = *(const short8*)(p + 256 + l * 8);
            float f = __int_as_float(w.y);
            #pragma unroll
            for (int q = 0; q < 8; q++) {
                va[q] += f * bf2f((unsigned short)A[q]);
                vb[q] += f * bf2f((unsigned short)B[q]);
            }
            if (tl) {
                short8 C = *(const short8*)(p + 512 + l * 8);
                #pragma unroll
                for (int q = 0; q < 8; q++) vc[q] += f * bf2f((unsigned short)C[q]);
            }
        }
    }
    for (; e < o1; e += 2) {
        int ee = e + h;
        bool valid = ee < o1;
        int2 w = cs[valid ? ee : e];
        float f = valid ? __int_as_float(w.y) : 0.f;
        const unsigned short* p = xb + (size_t)(unsigned)w.x * 560;
        short8 A = *(const short8*)(p + l * 8);
        short8 B = *(const short8*)(p + 256 + l * 8);
        #pragma unroll
        for (int q = 0; q < 8; q++) {
            va[q] += f * bf2f((unsigned short)A[q]);
            vb[q] += f * bf2f((unsigned short)B[q]);
        }
        if (tl) {
            short8 C = *(const short8*)(p + 512 + l * 8);
            #pragma unroll
            for (int q = 0; q < 8; q++) vc[q] += f * bf2f((unsigned short)C[q]);
        }
    }
    // combine halves
    #pragma unroll
    for (int q = 0; q < 8; q++) {
        va[q] += __shfl_xor(va[q], 32, 64);
        vb[q] += __shfl_xor(vb[q], 32, 64);
        vc[q] += __shfl_xor(vc[q], 32, 64);
    }
    if (h == 0) {
        short8 o2, o3;
        #pragma unroll
        for (int q = 0; q < 8; q++) {
            o2[q] = (short)f2bf(va[q] * ndv);
            o3[q] = (short)f2bf(vb[q] * ndv);
        }
        *(short8*)(Y2 + (size_t)bn * 2048 + r * 256 + l * 8) = o2;
        *(short8*)(Y3 + (size_t)bn * 2432 + r * 304 + l * 8) = o3;
        if (tl) {
            short8 oc;
            #pragma unroll
            for (int q = 0; q < 8; q++) oc[q] = (short)f2bf(vc[q] * ndv);
            *(short8*)(Y3 + (size_t)bn * 2432 + r * 304 + 256 + l * 8) = oc;
        }
    }
}

// ---------------- generic bf16 MFMA GEMM (r0-proven), used for G projection ----------------
// flags: 1=addbias, 2=accum(read Cin fp32), 4=relu, 8=out bf16 (else fp32)
template<int TN>
__global__ __launch_bounds__(256) void k_gemm_bf(
        const unsigned short* __restrict__ A, int lda,
        const unsigned short* __restrict__ BT, int ldb,
        const float* __restrict__ bias,
        const float* __restrict__ Cin, int ldcin,
        void* __restrict__ Cout, int ldc,
        int M, int K, int flags) {
    constexpr int BN = TN * 32;
    __shared__ unsigned short As[128 * 64];
    __shared__ unsigned short Bs[BN * 64];
    int m0 = blockIdx.x * 128;
    int n0 = blockIdx.y * BN;
    int t = threadIdx.x;
    int w = t >> 6, l = t & 63;
    int qm = (w >> 1) * 64, qn = (w & 1) * (TN * 16);
    int lr = l & 15, lg = l >> 4;
    int lrow = l >> 3;
    int lch  = (l & 7) ^ lrow;

    floatx4 acc[4][TN];
    #pragma unroll
    for (int a = 0; a < 4; a++)
        #pragma unroll
        for (int b = 0; b < TN; b++)
            acc[a][b] = (floatx4){0.f, 0.f, 0.f, 0.f};

    for (int k0 = 0; k0 < K; k0 += 64) {
        #pragma unroll
        for (int j = 0; j < 4; j++) {
            int seg = w * 4 + j;
            int gr = m0 + seg * 8 + lrow; if (gr > M - 1) gr = M - 1;
            gload_lds16(A + (size_t)gr * lda + k0 + lch * 8, &As[seg * 512]);
        }
        #pragma unroll
        for (int j = 0; j < TN; j++) {
            int seg = w * TN + j;
            int row = n0 + seg * 8 + lrow;
            gload_lds16(BT + (size_t)row * ldb + k0 + lch * 8, &Bs[seg * 512]);
        }
        __syncthreads();
        #pragma unroll
        for (int ks = 0; ks < 2; ks++) {
            int slot = ((ks * 4 + lg) ^ (lr & 7)) * 8;
            short8 af[4], bf[TN];
            #pragma unroll
            for (int i = 0; i < 4; i++)
                af[i] = *(const short8*)&As[(qm + i * 16 + lr) * 64 + slot];
            #pragma unroll
            for (int i = 0; i < TN; i++)
                bf[i] = *(const short8*)&Bs[(qn + i * 16 + lr) * 64 + slot];
            #pragma unroll
            for (int tm = 0; tm < 4; tm++)
                #pragma unroll
                for (int tn = 0; tn < TN; tn++)
                    acc[tm][tn] = __builtin_amdgcn_mfma_f32_16x16x32_bf16(
                        af[tm], bf[tn], acc[tm][tn], 0, 0, 0);
        }
        __syncthreads();
    }

    int addbias = flags & 1, accum = flags & 2, relu = flags & 4, outbf = flags & 8;
    #pragma unroll
    for (int tm = 0; tm < 4; tm++) {
        int rbase = m0 + qm + tm * 16 + lg * 4;
        #pragma unroll
        for (int reg = 0; reg < 4; reg++) {
            int row = rbase + reg;
            if (row >= M) continue;
            #pragma unroll
            for (int tn = 0; tn < TN; tn++) {
                int col = n0 + qn + tn * 16 + lr;
                float v = acc[tm][tn][reg];
                if (addbias) v += bias[col];
                if (accum) v += Cin[(size_t)row * ldcin + col];
                if (relu) v = fmaxf(v, 0.f);
                if (outbf) ((unsigned short*)Cout)[(size_t)row * ldc + col] = f2bf(v);
                else       ((float*)Cout)[(size_t)row * ldc + col] = v;
            }
        }
    }
}

// ---------------- paired a-layer GEMM: z=0 -> 2a (K=2048), z=1 -> 3a (K=2432) ----------------
__global__ __launch_bounds__(256) void k_gemm2(
        const unsigned short* __restrict__ Y2, const unsigned short* __restrict__ Y3,
        const unsigned short* __restrict__ WT2, const unsigned short* __restrict__ WT3,
        const float* __restrict__ bs, unsigned short* __restrict__ hb,
        int nbase, int M) {
    constexpr int TN = 2;
    __shared__ unsigned short As[128 * 64];
    __shared__ unsigned short Bs[64 * 64];
    int z = blockIdx.z;
    const unsigned short* A  = z ? Y3 : Y2;
    const unsigned short* BT = z ? WT3 : WT2;
    int lda = z ? 2432 : 2048;
    int K = lda;
    const float* bias = bs + z * 512;
    int m0 = blockIdx.x * 128;
    int n0 = blockIdx.y * 64;
    int t = threadIdx.x;
    int w = t >> 6, l = t & 63;
    int qm = (w >> 1) * 64, qn = (w & 1) * 32;
    int lr = l & 15, lg = l >> 4;
    int lrow = l >> 3;
    int lch  = (l & 7) ^ lrow;

    floatx4 acc[4][TN];
    #pragma unroll
    for (int a = 0; a < 4; a++)
        #pragma unroll
        for (int b = 0; b < TN; b++)
            acc[a][b] = (floatx4){0.f, 0.f, 0.f, 0.f};

    for (int k0 = 0; k0 < K; k0 += 64) {
        #pragma unroll
        for (int j = 0; j < 4; j++) {
            int seg = w * 4 + j;
            int gr = m0 + seg * 8 + lrow; if (gr > M - 1) gr = M - 1;
            gload_lds16(A + (size_t)gr * lda + k0 + lch * 8, &As[seg * 512]);
        }
        #pragma unroll
        for (int j = 0; j < TN; j++) {
            int seg = w * TN + j;
            int row = n0 + seg * 8 + lrow;
            gload_lds16(BT + (size_t)row * lda + k0 + lch * 8, &Bs[seg * 512]);
        }
        __syncthreads();
        #pragma unroll
        for (int ks = 0; ks < 2; ks++) {
            int slot = ((ks * 4 + lg) ^ (lr & 7)) * 8;
            short8 af[4], bf[TN];
            #pragma unroll
            for (int i = 0; i < 4; i++)
                af[i] = *(const short8*)&As[(qm + i * 16 + lr) * 64 + slot];
            #pragma unroll
            for (int i = 0; i < TN; i++)
                bf[i] = *(const short8*)&Bs[(qn + i * 16 + lr) * 64 + slot];
            #pragma unroll
            for (int tm = 0; tm < 4; tm++)
                #pragma unroll
                for (int tn = 0; tn < TN; tn++)
                    acc[tm][tn] = __builtin_amdgcn_mfma_f32_16x16x32_bf16(
                        af[tm], bf[tn], acc[tm][tn], 0, 0, 0);
        }
        __syncthreads();
    }

    #pragma unroll
    for (int tm = 0; tm < 4; tm++) {
        int rbase = m0 + qm + tm * 16 + lg * 4;
        #pragma unroll
        for (int reg = 0; reg < 4; reg++) {
            int row = rbase + reg;
            if (row >= M) continue;
            #pragma unroll
            for (int tn = 0; tn < TN; tn++) {
                int col = n0 + qn + tn * 16 + lr;
                float v = fmaxf(acc[tm][tn][reg] + bias[col], 0.f);
                hb[(size_t)(nbase + row) * 512 + z * 256 + col] = f2bf(v);
            }
        }
    }
}

// ---------------- 16-dim projected aggregation: AB[n, 0:16] (cvec folded into j<8) ------------
__global__ __launch_bounds__(256) void k_aggAB(
        const int2* __restrict__ csrw, const int* __restrict__ offs,
        const float* __restrict__ nd, const float* __restrict__ G,
        const float* __restrict__ cfold, const float* __restrict__ cvec,
        float* __restrict__ AB) {
    int lane = threadIdx.x & 63, sub = threadIdx.x >> 6;
    int n = blockIdx.x * 4 + sub;
    int slot = lane >> 4, j = lane & 15;
    float acc = 0.f;
    for (int r = 0; r < RR; r++) {
        int o0 = offs[r * (NN + 1) + n];
        int o1 = offs[r * (NN + 1) + n + 1];
        o0 = __builtin_amdgcn_readfirstlane(o0);
        o1 = __builtin_amdgcn_readfirstlane(o1);
        float ndv = nd[(size_t)r * NN + n];
        const int2* cs = csrw + (size_t)r * EE;
        float tr = 0.f;
        for (int e = o0 + slot; e < o1; e += 4) {
            int2 w = cs[e];
            tr += __int_as_float(w.y) * G[(size_t)(unsigned)w.x * 128 + r * 16 + j];
        }
        acc += ndv * tr;
    }
    acc += __shfl_xor(acc, 16, 64);
    acc += __shfl_xor(acc, 32, 64);
    if (lane < 16) AB[(size_t)n * 16 + j] = acc + cfold[j] + (j < 8 ? cvec[j] : 0.f);
}

// ---------------- per-edge decoder (float4, cvec pre-folded) ----------------
__global__ void k_dec(const int* __restrict__ dsrc, const int* __restrict__ ddst,
                      const float* __restrict__ AB, float* __restrict__ out) {
    int e = blockIdx.x * 256 + threadIdx.x;
    if (e >= EDD) return;
    int s = dsrc[e], d = ddst[e];
    const float4* as = (const float4*)(AB + (size_t)s * 16);
    const float4* ad = (const float4*)(AB + (size_t)d * 16 + 8);
    float4 x0 = as[0], x1 = as[1], y0 = ad[0], y1 = ad[1];
    float4 o0 = {x0.x + y0.x, x0.y + y0.y, x0.z + y0.z, x0.w + y0.w};
    float4 o1 = {x1.x + y1.x, x1.y + y1.y, x1.z + y1.z, x1.w + y1.w};
    float4* op = (float4*)(out + (size_t)e * 8);
    op[0] = o0; op[1] = o1;
}

extern "C" void kernel_launch(void* const* d_in, const int* in_sizes, int n_in,
                              void* d_out, int out_size, void* d_ws, size_t ws_size,
                              hipStream_t stream) {
    const float* x2  = (const float*)d_in[0];
    const float* x3  = (const float*)d_in[1];
    const int*   src = (const int*)d_in[2];
    const int*   dst = (const int*)d_in[3];
    const int*   dsrc = (const int*)d_in[4];
    const int*   ddst = (const int*)d_in[5];
    const float* W2a = (const float*)d_in[6];
    const float* b2a = (const float*)d_in[7];
    const float* W2b = (const float*)d_in[8];
    const float* b2b = (const float*)d_in[9];
    const float* W3a = (const float*)d_in[10];
    const float* b3a = (const float*)d_in[11];
    const float* W3b = (const float*)d_in[12];
    const float* b3b = (const float*)d_in[13];
    const float* Wp1 = (const float*)d_in[14];
    const float* bp1 = (const float*)d_in[15];
    const float* Wp2 = (const float*)d_in[16];
    const float* bp2 = (const float*)d_in[17];
    float* out = (float*)d_out;

    // ---- workspace layout (~172 MB < proven 182.4 MB bound) ----
    char* ws = (char*)d_ws;
    size_t off = 0;
    auto alloc = [&](size_t nbytes) {
        char* p = ws + off;
        off += nbytes;
        off = (off + 255) & ~(size_t)255;
        return p;
    };
    float* ns   = (float*)alloc((size_t)RR * NN * 4);        // aliases outdeg
    float* nd   = (float*)alloc((size_t)RR * NN * 4);        // aliases indeg
    int*   offs = (int*)alloc((size_t)RR * (NN + 1) * 4);
    int2*  csrw = (int2*)alloc((size_t)RR * EE * 8);
    unsigned short* XH     = (unsigned short*)alloc((size_t)NN * 560 * 2);  // [x2|x3|pad] interleaved
    unsigned short* hbuf23 = (unsigned short*)alloc((size_t)NN * 512 * 2);  // [h2a|h3a] interleaved
    unsigned short* WT2a   = (unsigned short*)alloc((size_t)256 * 2048 * 2);
    unsigned short* WT3a   = (unsigned short*)alloc((size_t)256 * 2432 * 2);
    unsigned short* FmatT  = (unsigned short*)alloc((size_t)128 * 512 * 2);
    char* YR = alloc((size_t)CH * (2048 + 2432) * 2);        // Y2a|Y3a; also cursor/tmp/G/AB
    float* Mcat  = (float*)alloc(4096 * 4);
    float* cvec  = (float*)alloc(64 * 4);
    float* bsums = (float*)alloc(1024 * 4);
    float* cfold = (float*)alloc(64 * 4);
    int*   bsum  = (int*)alloc((size_t)RR * SCB * 4);

    unsigned short* Y2a = (unsigned short*)YR;
    unsigned short* Y3a = Y2a + (size_t)CH * 2048;
    int*   outdeg = (int*)ns;
    int*   indeg  = (int*)nd;
    int*   cursor = (int*)YR;                              // live only until k_fillw
    unsigned char* htmp = (unsigned char*)(YR + (4 << 20)); // 12.8 MB, live during histp/reduce
    float* G      = (float*)YR;                            // [NN x 128] f32, live after phase a
    float* AB     = (float*)(YR + (size_t)NN * 128 * 4);   // 3.2 MB after G

    // ---- graph prep ----
    hipMemsetAsync(cursor, 0, (size_t)RR * NN * 4, stream);

    k_histp<<<dim3(CHK, RR, 2), 256, 0, stream>>>(src, dst, htmp);
    k_reduce<<<(2 * RR * 12512 + 255) / 256, 256, 0, stream>>>(htmp, outdeg, indeg);
    k_scanA<<<dim3(SCB, RR), 256, 0, stream>>>(indeg, bsum);
    k_scanB<<<RR, 256, 0, stream>>>(bsum, offs);
    k_scanC<<<dim3(SCB, RR), 256, 0, stream>>>(indeg, bsum, offs);
    k_norms<<<(RR * NN + 255) / 256, 256, 0, stream>>>(outdeg, indeg);
    int edgeBlocks = (RR * EE + 255) / 256;
    k_fillw<<<edgeBlocks, 256, 0, stream>>>(src, dst, offs, ns, cursor, csrw);
    k_prep<<<18, 256, 0, stream>>>(Wp1, Wp2, bp1, bp2, b2a, b2b, b3a, b3b, Mcat, cvec, bsums);
    k_fold<<<257, 256, 0, stream>>>(W2b, W3b, Mcat, bsums, FmatT, cfold);

    k_castx<<<(NN * 560 + 255) / 256, 256, 0, stream>>>(x2, x3, XH);
    k_wt2<<<dim3((256 * RR * 304 + 255) / 256, 2), 256, 0, stream>>>(W2a, W3a, WT2a, WT3a);

    // ---- phase a: chunked dual aggregation + paired GEMM -> hbuf23 (relu bf16) ----
    for (int c = 0; c < NN / CH; c++) {
        k_aggp<<<dim3(CH / 4, RR), 256, 0, stream>>>(XH, csrw, offs, nd, c * CH, Y2a, Y3a);
        k_gemm2<<<dim3((CH + 127) / 128, 4, 2), 256, 0, stream>>>(
            Y2a, Y3a, WT2a, WT3a, bsums, hbuf23, c * CH, CH);
    }

    // ---- phase b (folded): G = hbuf23 @ FmatT^T  [NN x 128] f32 ----
    k_gemm_bf<1><<<dim3((NN + 127) / 128, 4), 256, 0, stream>>>(
        hbuf23, 512, FmatT, 512, bsums, (const float*)nullptr, 0,
        (void*)G, 128, NN, 512, 0);

    // ---- projected aggregation -> AB, then decoder ----
    k_aggAB<<<NN / 4, 256, 0, stream>>>(csrw, offs, nd, G, cfold, cvec, AB);
    k_dec<<<(EDD + 255) / 256, 256, 0, stream>>>(dsrc, ddst, AB, out);
}

// Round 5
// 1157.769 us; speedup vs baseline: 1.8393x; 1.0325x over previous
//
#include <hip/hip_runtime.h>
#include <hip/hip_bf16.h>

#define NN 50000
#define RR 8
#define EE 200000
#define EDD 400000
#define SCB 196   // ceil(NN/256) scan blocks
#define CH 5000   // phase-a node chunk (10 chunks)
#define CHK 16    // histogram privatization chunks

typedef __attribute__((ext_vector_type(8))) short short8;
typedef __attribute__((ext_vector_type(4))) float floatx4;

static __device__ __forceinline__ unsigned short f2bf(float f) {
    union { float f; unsigned u; } v; v.f = f;
    unsigned r = v.u + 0x7fff + ((v.u >> 16) & 1);
    return (unsigned short)(r >> 16);
}
static __device__ __forceinline__ float bf2f(unsigned short h) {
    union { unsigned u; float f; } v; v.u = ((unsigned)h) << 16;
    return v.f;
}
// async global->LDS, 16B per lane; LDS dest = uniform base + lane*16
static __device__ __forceinline__ void gload_lds16(const unsigned short* g, unsigned short* l) {
    __builtin_amdgcn_global_load_lds(
        (const __attribute__((address_space(1))) void*)g,
        (__attribute__((address_space(3))) void*)l,
        16, 0, 0);
}

// ---------------- privatized degree histogram: 8-bit LDS bins, non-atomic flush ----------------
__global__ __launch_bounds__(256) void k_histp(const int* __restrict__ src, const int* __restrict__ dst,
                                               unsigned char* __restrict__ tmp) {
    __shared__ unsigned lh[12512];   // 50048 bytes, 8-bit bins
    int chunk = blockIdx.x, r = blockIdx.y, which = blockIdx.z;
    const int* idx = (which ? dst : src) + (size_t)r * EE;
    for (int i = threadIdx.x; i < 12512; i += 256) lh[i] = 0;
    __syncthreads();
    int e0 = chunk * (EE / CHK);
    for (int e = e0 + threadIdx.x; e < e0 + EE / CHK; e += 256) {
        int n = idx[e];
        atomicAdd(&lh[n >> 2], 1u << ((n & 3) * 8));
    }
    __syncthreads();
    unsigned* t = (unsigned*)(tmp + (((size_t)(which * RR + r) * CHK + chunk) * 50048));
    for (int i = threadIdx.x; i < 12512; i += 256) t[i] = lh[i];
}

// ---------------- reduce the CHK private copies -> int degree arrays ----------------
__global__ void k_reduce(const unsigned char* __restrict__ tmp,
                         int* __restrict__ outdeg, int* __restrict__ indeg) {
    int i = blockIdx.x * 256 + threadIdx.x;
    if (i >= 2 * RR * 12512) return;
    int wr = i / 12512;        // which*RR + r
    int wd = i - wr * 12512;   // word index (4 nodes)
    unsigned s0 = 0, s1 = 0, s2 = 0, s3 = 0;
    const unsigned* base = (const unsigned*)(tmp + (size_t)wr * CHK * 50048) + wd;
    #pragma unroll
    for (int c = 0; c < CHK; c++) {
        unsigned v = base[(size_t)c * 12512];
        s0 += v & 255u; s1 += (v >> 8) & 255u; s2 += (v >> 16) & 255u; s3 += (v >> 24) & 255u;
    }
    int which = wr / RR, r = wr - which * RR;
    int n = wd * 4;
    int* deg = (which ? indeg : outdeg) + (size_t)r * NN;
    if (n < NN) {
        deg[n] = (int)s0;
        if (n + 1 < NN) deg[n + 1] = (int)s1;
        if (n + 2 < NN) deg[n + 2] = (int)s2;
        if (n + 3 < NN) deg[n + 3] = (int)s3;
    }
}

// ---------------- norms: in-place int degree -> float rsqrt ----------------
__global__ void k_norms(int* __restrict__ outdeg, int* __restrict__ indeg) {
    int i = blockIdx.x * blockDim.x + threadIdx.x;
    if (i >= RR * NN) return;
    int od = outdeg[i];
    int id = indeg[i];
    ((float*)outdeg)[i] = od > 0 ? rsqrtf((float)od) : 0.f;
    ((float*)indeg)[i]  = id > 0 ? rsqrtf((float)id) : 0.f;
}

// ---------------- parallel scan: phase A (per-block sums) ----------------
__global__ void k_scanA(const int* __restrict__ indeg, int* __restrict__ bsum) {
    int r = blockIdx.y;
    int i = blockIdx.x * 256 + threadIdx.x;
    int v = (i < NN) ? indeg[(size_t)r * NN + i] : 0;
    #pragma unroll
    for (int d = 32; d > 0; d >>= 1) v += __shfl_down(v, d, 64);
    __shared__ int ws4[4];
    if ((threadIdx.x & 63) == 0) ws4[threadIdx.x >> 6] = v;
    __syncthreads();
    if (threadIdx.x == 0) bsum[r * SCB + blockIdx.x] = ws4[0] + ws4[1] + ws4[2] + ws4[3];
}

// ---------------- phase B: exclusive scan of SCB block sums per relation ----------------
__global__ void k_scanB(int* __restrict__ bsum, int* __restrict__ offs) {
    int r = blockIdx.x;
    int t = threadIdx.x;
    int v = (t < SCB) ? bsum[r * SCB + t] : 0;
    int lane = t & 63, wid = t >> 6;
    int sv = v;
    #pragma unroll
    for (int d = 1; d < 64; d <<= 1) {
        int u = __shfl_up(sv, d, 64);
        if (lane >= d) sv += u;
    }
    __shared__ int wsum[4];
    if (lane == 63) wsum[wid] = sv;
    __syncthreads();
    int add = 0;
    for (int x = 0; x < wid; x++) add += wsum[x];
    int incl = sv + add;
    if (t < SCB) bsum[r * SCB + t] = incl - v;
    if (t == 255) offs[(size_t)r * (NN + 1) + NN] = incl;  // grand total
}

// ---------------- phase C: intra-block exclusive scan + base ----------------
__global__ void k_scanC(const int* __restrict__ indeg, const int* __restrict__ bsum,
                        int* __restrict__ offs) {
    int r = blockIdx.y;
    int i = blockIdx.x * 256 + threadIdx.x;
    int v = (i < NN) ? indeg[(size_t)r * NN + i] : 0;
    int lane = threadIdx.x & 63, wid = threadIdx.x >> 6;
    int sv = v;
    #pragma unroll
    for (int d = 1; d < 64; d <<= 1) {
        int u = __shfl_up(sv, d, 64);
        if (lane >= d) sv += u;
    }
    __shared__ int wsum[4];
    if (lane == 63) wsum[wid] = sv;
    __syncthreads();
    int add = bsum[r * SCB + blockIdx.x];
    for (int x = 0; x < wid; x++) add += wsum[x];
    if (i < NN) offs[(size_t)r * (NN + 1) + i] = sv - v + add;
}

// ---------------- fill CSR with fused src-norm weight: (src, ns[r][src]) ----------------
__global__ void k_fillw(const int* __restrict__ src, const int* __restrict__ dst,
                        const int* __restrict__ offs, const float* __restrict__ ns,
                        int* __restrict__ cursor, int2* __restrict__ csrw) {
    int i = blockIdx.x * blockDim.x + threadIdx.x;
    if (i >= RR * EE) return;
    int r = i / EE;
    int s = src[i], d = dst[i];
    int pos = offs[r * (NN + 1) + d] + atomicAdd(&cursor[r * NN + d], 1);
    int2 v;
    v.x = s;
    v.y = __float_as_int(ns[(size_t)r * NN + s]);
    csrw[(size_t)r * EE + pos] = v;
}

// ---------------- decoder prep (Mcat, cvec) + bias sums, one launch ----------------
__global__ void k_prep(const float* __restrict__ Wp1, const float* __restrict__ Wp2,
                       const float* __restrict__ bp1, const float* __restrict__ bp2,
                       const float* __restrict__ b2a, const float* __restrict__ b2b,
                       const float* __restrict__ b3a, const float* __restrict__ b3b,
                       float* __restrict__ Mcat, float* __restrict__ cvec,
                       float* __restrict__ bs) {
    int bx = blockIdx.x;
    if (bx < 16) {
        int t = bx * 256 + threadIdx.x;      // 4096 elements
        int i = t >> 4, j = t & 15;
        int half = j >> 3, jj = j & 7;
        const float* wrow = Wp1 + (size_t)(half * 256 + i) * 256;
        float s = 0.f;
        for (int k = 0; k < 256; k++) s += wrow[k] * Wp2[k * 8 + jj];
        Mcat[i * 16 + j] = s;
    } else if (bx == 16) {
        int j = threadIdx.x;
        if (j < 8) {
            float s = bp2[j];
            for (int k = 0; k < 256; k++) s += bp1[k] * Wp2[k * 8 + j];
            cvec[j] = s;
        }
    } else {
        int j = threadIdx.x;  // 256
        float s = 0.f;
        for (int r = 0; r < RR; r++) s += b2a[r * 256 + j];
        bs[j] = s;
        if (j < 128) {
            s = 0.f;
            for (int r = 0; r < RR; r++) s += b2b[r * 128 + j];
            bs[256 + j] = s;
        }
        s = 0.f;
        for (int r = 0; r < RR; r++) s += b3a[r * 256 + j];
        bs[512 + j] = s;
        if (j < 128) {
            s = 0.f;
            for (int r = 0; r < RR; r++) s += b3b[r * 128 + j];
            bs[768 + j] = s;
        }
    }
}

// ---------------- fold b-layer weights through decoder: FmatT[128][512] bf16, cfold[16] ----
__global__ void k_fold(const float* __restrict__ W2b, const float* __restrict__ W3b,
                       const float* __restrict__ Mcat, const float* __restrict__ bs,
                       unsigned short* __restrict__ FmatT, float* __restrict__ cfold) {
    int bx = blockIdx.x;
    if (bx < 256) {
        int idx = bx * 256 + threadIdx.x;      // 65536 = 128 rows x 512 cols
        int rj = idx >> 9, i = idx & 511;
        int r = rj >> 4, j = rj & 15;
        float s = 0.f;
        if (i < 256) {
            const float* wr = W2b + ((size_t)r * 256 + i) * 128;
            for (int c = 0; c < 128; c++) s += wr[c] * Mcat[c * 16 + j];
        } else {
            const float* wr = W3b + ((size_t)r * 256 + (i - 256)) * 128;
            for (int c = 0; c < 128; c++) s += wr[c] * Mcat[(128 + c) * 16 + j];
        }
        FmatT[(size_t)rj * 512 + i] = f2bf(s);
    } else {
        int j = threadIdx.x;
        if (j < 16) {
            float s = 0.f;
            for (int c = 0; c < 128; c++)
                s += bs[256 + c] * Mcat[c * 16 + j] + bs[768 + c] * Mcat[(128 + c) * 16 + j];
            cfold[j] = s;
        }
    }
}

// ---------------- interleaved bf16 cast: XH[m] = [x2(256) | x3(300) | 0 x4], stride 560 ----
__global__ void k_castx(const float* __restrict__ x2, const float* __restrict__ x3,
                        unsigned short* __restrict__ XH) {
    int i = blockIdx.x * 256 + threadIdx.x;
    if (i >= NN * 560) return;
    int row = i / 560, col = i - row * 560;
    float v;
    if (col < 256) v = x2[(size_t)row * 256 + col];
    else if (col < 556) v = x3[(size_t)row * 300 + (col - 256)];
    else v = 0.f;
    XH[i] = f2bf(v);
}

// ---------------- weight transposes (a-layers only): WT[n][r][kpad] bf16 ----------------
__global__ void k_wt2(const float* __restrict__ W2a, const float* __restrict__ W3a,
                      unsigned short* __restrict__ WT2, unsigned short* __restrict__ WT3) {
    const float* W; unsigned short* WT; int K0, Kpad;
    if (blockIdx.y == 0) { W = W2a; WT = WT2; K0 = 256; Kpad = 256; }
    else                 { W = W3a; WT = WT3; K0 = 300; Kpad = 304; }
    int i = blockIdx.x * 256 + threadIdx.x;
    int total = 256 * RR * Kpad;
    if (i >= total) return;
    int n = i / (RR * Kpad);
    int rem = i - n * (RR * Kpad);
    int r = rem / Kpad;
    int k = rem - r * Kpad;
    float v = (k < K0) ? W[((size_t)r * K0 + k) * 256 + n] : 0.f;
    WT[i] = f2bf(v);
}

// ---------------- dual-payload aggregation v3: record-broadcast gather ----------------
// Wave per (node, r). 64 CSR records preloaded in ONE coalesced load, shfl-broadcast.
// Always-taken 8-edge unrolled body (4/half-wave, OOB weight-clamped to 0):
// 12 independent 1KB row-loads in flight regardless of degree (Poisson(4)).
__global__ __launch_bounds__(256) void k_aggp(
        const unsigned short* __restrict__ xb,
        const int2* __restrict__ csrw, const int* __restrict__ offs,
        const float* __restrict__ nd, int nbase,
        unsigned short* __restrict__ Y2, unsigned short* __restrict__ Y3) {
    int lane = threadIdx.x & 63;
    int sub = threadIdx.x >> 6;
    int h = lane >> 5;           // half index (edge parity)
    int l = lane & 31;           // lane within half: col octet
    int bn = blockIdx.x * 4 + sub;
    int n = nbase + bn;
    int r = blockIdx.y;
    int o0 = offs[r * (NN + 1) + n];
    int o1 = offs[r * (NN + 1) + n + 1];
    o0 = __builtin_amdgcn_readfirstlane(o0);
    o1 = __builtin_amdgcn_readfirstlane(o1);
    int cnt = o1 - o0;
    float ndv = nd[(size_t)r * NN + n];
    const int2* cs = csrw + (size_t)r * EE + o0;
    bool tl = l < 6;             // x3 tail cols 512..559 handled by 6 lanes
    float va[8], vb[8], vc[8];
    #pragma unroll
    for (int q = 0; q < 8; q++) { va[q] = 0.f; vb[q] = 0.f; vc[q] = 0.f; }

    for (int eb = 0; eb < cnt; eb += 64) {
        int rem = cnt - eb;                        // > 0
        int2 rec = cs[eb + min(lane, rem - 1)];    // coalesced record block
        int kmax = rem < 64 ? rem : 64;
        for (int kb = 0; kb < kmax; kb += 8) {
            #pragma unroll
            for (int u = 0; u < 4; u++) {
                int k = kb + 2 * u + h;
                int kk = k < kmax - 1 ? k : kmax - 1;
                int sidx = __shfl(rec.x, kk, 64);
                float f = __int_as_float(__shfl(rec.y, kk, 64));
                if (k >= kmax) f = 0.f;
                const unsigned short* p = xb + (size_t)(unsigned)sidx * 560;
                short8 A = *(const short8*)(p + l * 8);
                short8 B = *(const short8*)(p + 256 + l * 8);
                #pragma unroll
                for (int q = 0; q < 8; q++) {
                    va[q] += f * bf2f((unsigned short)A[q]);
                    vb[q] += f * bf2f((unsigned short)B[q]);
                }
                if (tl) {
                    short8 C = *(const short8*)(p + 512 + l * 8);
                    #pragma unroll
                    for (int q = 0; q < 8; q++) vc[q] += f * bf2f((unsigned short)C[q]);
                }
            }
        }
    }
    // combine halves
    #pragma unroll
    for (int q = 0; q < 8; q++) {
        va[q] += __shfl_xor(va[q], 32, 64);
        vb[q] += __shfl_xor(vb[q], 32, 64);
        vc[q] += __shfl_xor(vc[q], 32, 64);
    }
    if (h == 0) {
        short8 o2, o3;
        #pragma unroll
        for (int q = 0; q < 8; q++) {
            o2[q] = (short)f2bf(va[q] * ndv);
            o3[q] = (short)f2bf(vb[q] * ndv);
        }
        *(short8*)(Y2 + (size_t)bn * 2048 + r * 256 + l * 8) = o2;
        *(short8*)(Y3 + (size_t)bn * 2432 + r * 304 + l * 8) = o3;
        if (tl) {
            short8 oc;
            #pragma unroll
            for (int q = 0; q < 8; q++) oc[q] = (short)f2bf(vc[q] * ndv);
            *(short8*)(Y3 + (size_t)bn * 2432 + r * 304 + 256 + l * 8) = oc;
        }
    }
}

// ---------------- generic bf16 MFMA GEMM (r0-proven), used for G projection ----------------
// flags: 1=addbias, 2=accum(read Cin fp32), 4=relu, 8=out bf16 (else fp32)
template<int TN>
__global__ __launch_bounds__(256) void k_gemm_bf(
        const unsigned short* __restrict__ A, int lda,
        const unsigned short* __restrict__ BT, int ldb,
        const float* __restrict__ bias,
        const float* __restrict__ Cin, int ldcin,
        void* __restrict__ Cout, int ldc,
        int M, int K, int flags) {
    constexpr int BN = TN * 32;
    __shared__ unsigned short As[128 * 64];
    __shared__ unsigned short Bs[BN * 64];
    int m0 = blockIdx.x * 128;
    int n0 = blockIdx.y * BN;
    int t = threadIdx.x;
    int w = t >> 6, l = t & 63;
    int qm = (w >> 1) * 64, qn = (w & 1) * (TN * 16);
    int lr = l & 15, lg = l >> 4;
    int lrow = l >> 3;
    int lch  = (l & 7) ^ lrow;

    floatx4 acc[4][TN];
    #pragma unroll
    for (int a = 0; a < 4; a++)
        #pragma unroll
        for (int b = 0; b < TN; b++)
            acc[a][b] = (floatx4){0.f, 0.f, 0.f, 0.f};

    for (int k0 = 0; k0 < K; k0 += 64) {
        #pragma unroll
        for (int j = 0; j < 4; j++) {
            int seg = w * 4 + j;
            int gr = m0 + seg * 8 + lrow; if (gr > M - 1) gr = M - 1;
            gload_lds16(A + (size_t)gr * lda + k0 + lch * 8, &As[seg * 512]);
        }
        #pragma unroll
        for (int j = 0; j < TN; j++) {
            int seg = w * TN + j;
            int row = n0 + seg * 8 + lrow;
            gload_lds16(BT + (size_t)row * ldb + k0 + lch * 8, &Bs[seg * 512]);
        }
        __syncthreads();
        #pragma unroll
        for (int ks = 0; ks < 2; ks++) {
            int slot = ((ks * 4 + lg) ^ (lr & 7)) * 8;
            short8 af[4], bf[TN];
            #pragma unroll
            for (int i = 0; i < 4; i++)
                af[i] = *(const short8*)&As[(qm + i * 16 + lr) * 64 + slot];
            #pragma unroll
            for (int i = 0; i < TN; i++)
                bf[i] = *(const short8*)&Bs[(qn + i * 16 + lr) * 64 + slot];
            #pragma unroll
            for (int tm = 0; tm < 4; tm++)
                #pragma unroll
                for (int tn = 0; tn < TN; tn++)
                    acc[tm][tn] = __builtin_amdgcn_mfma_f32_16x16x32_bf16(
                        af[tm], bf[tn], acc[tm][tn], 0, 0, 0);
        }
        __syncthreads();
    }

    int addbias = flags & 1, accum = flags & 2, relu = flags & 4, outbf = flags & 8;
    #pragma unroll
    for (int tm = 0; tm < 4; tm++) {
        int rbase = m0 + qm + tm * 16 + lg * 4;
        #pragma unroll
        for (int reg = 0; reg < 4; reg++) {
            int row = rbase + reg;
            if (row >= M) continue;
            #pragma unroll
            for (int tn = 0; tn < TN; tn++) {
                int col = n0 + qn + tn * 16 + lr;
                float v = acc[tm][tn][reg];
                if (addbias) v += bias[col];
                if (accum) v += Cin[(size_t)row * ldcin + col];
                if (relu) v = fmaxf(v, 0.f);
                if (outbf) ((unsigned short*)Cout)[(size_t)row * ldc + col] = f2bf(v);
                else       ((float*)Cout)[(size_t)row * ldc + col] = v;
            }
        }
    }
}

// ---------------- paired a-layer GEMM, BM=64/BN=64 (632 blocks -> no tail quantization) ------
// z=0 -> 2a (K=2048), z=1 -> 3a (K=2432); out hb[(nbase+row)*512 + z*256 + col] relu bf16
__global__ __launch_bounds__(256) void k_gemm2(
        const unsigned short* __restrict__ Y2, const unsigned short* __restrict__ Y3,
        const unsigned short* __restrict__ WT2, const unsigned short* __restrict__ WT3,
        const float* __restrict__ bs, unsigned short* __restrict__ hb,
        int nbase, int M) {
    __shared__ unsigned short As[64 * 64];
    __shared__ unsigned short Bs[64 * 64];
    int z = blockIdx.z;
    const unsigned short* A  = z ? Y3 : Y2;
    const unsigned short* BT = z ? WT3 : WT2;
    int lda = z ? 2432 : 2048;
    int K = lda;
    const float* bias = bs + z * 512;
    int m0 = blockIdx.x * 64;
    int n0 = blockIdx.y * 64;
    int t = threadIdx.x;
    int w = t >> 6, l = t & 63;
    int qm = (w >> 1) * 32, qn = (w & 1) * 32;
    int lr = l & 15, lg = l >> 4;
    int lrow = l >> 3;
    int lch  = (l & 7) ^ lrow;

    floatx4 acc[2][2];
    #pragma unroll
    for (int a = 0; a < 2; a++)
        #pragma unroll
        for (int b = 0; b < 2; b++)
            acc[a][b] = (floatx4){0.f, 0.f, 0.f, 0.f};

    for (int k0 = 0; k0 < K; k0 += 64) {
        #pragma unroll
        for (int j = 0; j < 2; j++) {
            int seg = w * 2 + j;                   // 8 segs x 8 rows = 64 rows
            int gr = m0 + seg * 8 + lrow; if (gr > M - 1) gr = M - 1;
            gload_lds16(A + (size_t)gr * lda + k0 + lch * 8, &As[seg * 512]);
        }
        #pragma unroll
        for (int j = 0; j < 2; j++) {
            int seg = w * 2 + j;
            int row = n0 + seg * 8 + lrow;         // <= 255, WT has 256 rows
            gload_lds16(BT + (size_t)row * lda + k0 + lch * 8, &Bs[seg * 512]);
        }
        __syncthreads();
        #pragma unroll
        for (int ks = 0; ks < 2; ks++) {
            int slot = ((ks * 4 + lg) ^ (lr & 7)) * 8;
            short8 af[2], bf[2];
            #pragma unroll
            for (int i = 0; i < 2; i++)
                af[i] = *(const short8*)&As[(qm + i * 16 + lr) * 64 + slot];
            #pragma unroll
            for (int i = 0; i < 2; i++)
                bf[i] = *(const short8*)&Bs[(qn + i * 16 + lr) * 64 + slot];
            #pragma unroll
            for (int tm = 0; tm < 2; tm++)
                #pragma unroll
                for (int tn = 0; tn < 2; tn++)
                    acc[tm][tn] = __builtin_amdgcn_mfma_f32_16x16x32_bf16(
                        af[tm], bf[tn], acc[tm][tn], 0, 0, 0);
        }
        __syncthreads();
    }

    #pragma unroll
    for (int tm = 0; tm < 2; tm++) {
        int rbase = m0 + qm + tm * 16 + lg * 4;
        #pragma unroll
        for (int reg = 0; reg < 4; reg++) {
            int row = rbase + reg;
            if (row >= M) continue;
            #pragma unroll
            for (int tn = 0; tn < 2; tn++) {
                int col = n0 + qn + tn * 16 + lr;
                float v = fmaxf(acc[tm][tn][reg] + bias[col], 0.f);
                hb[(size_t)(nbase + row) * 512 + z * 256 + col] = f2bf(v);
            }
        }
    }
}

// ---------------- 16-dim projected aggregation v2: slot = relation pairs, rec-broadcast ------
// AB[n,j] = cfold[j] + [j<8]cvec[j] + sum_r nd_r[n] * sum_e ns_e * G[src_e*128 + r*16 + j]
__global__ __launch_bounds__(256) void k_aggAB(
        const int2* __restrict__ csrw, const int* __restrict__ offs,
        const float* __restrict__ nd, const float* __restrict__ G,
        const float* __restrict__ cfold, const float* __restrict__ cvec,
        float* __restrict__ AB) {
    int lane = threadIdx.x & 63, sub = threadIdx.x >> 6;
    int n = blockIdx.x * 4 + sub;
    int slot = lane >> 4, j = lane & 15;
    int jb = slot << 4;                     // group base lane for shfl
    float acc = 0.f;
    for (int hh = 0; hh < 2; hh++) {
        int r = slot + hh * 4;
        int o0 = offs[r * (NN + 1) + n];
        int o1 = offs[r * (NN + 1) + n + 1];
        float ndv = nd[(size_t)r * NN + n];
        const int2* cs = csrw + (size_t)r * EE + o0;
        int cnt = o1 - o0;
        float t0 = 0.f, t1 = 0.f;
        for (int eb = 0; eb < cnt; eb += 16) {
            int rem = cnt - eb;
            int2 rec = cs[eb + min(j, rem - 1)];   // 16 records per slot, coalesced
            int kmax = rem < 16 ? rem : 16;
            for (int k = 0; k < kmax; k += 2) {
                int s0 = __shfl(rec.x, jb + k, 64);
                float f0 = __int_as_float(__shfl(rec.y, jb + k, 64));
                int k1 = k + 1 < kmax ? k + 1 : kmax - 1;
                int s1 = __shfl(rec.x, jb + k1, 64);
                float f1 = (k + 1 < kmax) ? __int_as_float(__shfl(rec.y, jb + k1, 64)) : 0.f;
                t0 += f0 * G[(size_t)(unsigned)s0 * 128 + r * 16 + j];
                t1 += f1 * G[(size_t)(unsigned)s1 * 128 + r * 16 + j];
            }
        }
        acc += ndv * (t0 + t1);
    }
    acc += __shfl_xor(acc, 16, 64);
    acc += __shfl_xor(acc, 32, 64);
    if (lane < 16) AB[(size_t)n * 16 + j] = acc + cfold[j] + (j < 8 ? cvec[j] : 0.f);
}

// ---------------- per-edge decoder (float4, cvec pre-folded) ----------------
__global__ void k_dec(const int* __restrict__ dsrc, const int* __restrict__ ddst,
                      const float* __restrict__ AB, float* __restrict__ out) {
    int e = blockIdx.x * 256 + threadIdx.x;
    if (e >= EDD) return;
    int s = dsrc[e], d = ddst[e];
    const float4* as = (const float4*)(AB + (size_t)s * 16);
    const float4* ad = (const float4*)(AB + (size_t)d * 16 + 8);
    float4 x0 = as[0], x1 = as[1], y0 = ad[0], y1 = ad[1];
    float4 o0 = {x0.x + y0.x, x0.y + y0.y, x0.z + y0.z, x0.w + y0.w};
    float4 o1 = {x1.x + y1.x, x1.y + y1.y, x1.z + y1.z, x1.w + y1.w};
    float4* op = (float4*)(out + (size_t)e * 8);
    op[0] = o0; op[1] = o1;
}

extern "C" void kernel_launch(void* const* d_in, const int* in_sizes, int n_in,
                              void* d_out, int out_size, void* d_ws, size_t ws_size,
                              hipStream_t stream) {
    const float* x2  = (const float*)d_in[0];
    const float* x3  = (const float*)d_in[1];
    const int*   src = (const int*)d_in[2];
    const int*   dst = (const int*)d_in[3];
    const int*   dsrc = (const int*)d_in[4];
    const int*   ddst = (const int*)d_in[5];
    const float* W2a = (const float*)d_in[6];
    const float* b2a = (const float*)d_in[7];
    const float* W2b = (const float*)d_in[8];
    const float* b2b = (const float*)d_in[9];
    const float* W3a = (const float*)d_in[10];
    const float* b3a = (const float*)d_in[11];
    const float* W3b = (const float*)d_in[12];
    const float* b3b = (const float*)d_in[13];
    const float* Wp1 = (const float*)d_in[14];
    const float* bp1 = (const float*)d_in[15];
    const float* Wp2 = (const float*)d_in[16];
    const float* bp2 = (const float*)d_in[17];
    float* out = (float*)d_out;

    // ---- workspace layout (~172 MB < proven 182.4 MB bound) ----
    char* ws = (char*)d_ws;
    size_t off = 0;
    auto alloc = [&](size_t nbytes) {
        char* p = ws + off;
        off += nbytes;
        off = (off + 255) & ~(size_t)255;
        return p;
    };
    float* ns   = (float*)alloc((size_t)RR * NN * 4);        // aliases outdeg
    float* nd   = (float*)alloc((size_t)RR * NN * 4);        // aliases indeg
    int*   offs = (int*)alloc((size_t)RR * (NN + 1) * 4);
    int2*  csrw = (int2*)alloc((size_t)RR * EE * 8);
    unsigned short* XH     = (unsigned short*)alloc((size_t)NN * 560 * 2);  // [x2|x3|pad] interleaved
    unsigned short* hbuf23 = (unsigned short*)alloc((size_t)NN * 512 * 2);  // [h2a|h3a] interleaved
    unsigned short* WT2a   = (unsigned short*)alloc((size_t)256 * 2048 * 2);
    unsigned short* WT3a   = (unsigned short*)alloc((size_t)256 * 2432 * 2);
    unsigned short* FmatT  = (unsigned short*)alloc((size_t)128 * 512 * 2);
    char* YR = alloc((size_t)CH * (2048 + 2432) * 2);        // Y2a|Y3a; also cursor/tmp/G/AB
    float* Mcat  = (float*)alloc(4096 * 4);
    float* cvec  = (float*)alloc(64 * 4);
    float* bsums = (float*)alloc(1024 * 4);
    float* cfold = (float*)alloc(64 * 4);
    int*   bsum  = (int*)alloc((size_t)RR * SCB * 4);

    unsigned short* Y2a = (unsigned short*)YR;
    unsigned short* Y3a = Y2a + (size_t)CH * 2048;
    int*   outdeg = (int*)ns;
    int*   indeg  = (int*)nd;
    int*   cursor = (int*)YR;                              // live only until k_fillw
    unsigned char* htmp = (unsigned char*)(YR + (4 << 20)); // 12.8 MB, live during histp/reduce
    float* G      = (float*)YR;                            // [NN x 128] f32, live after phase a
    float* AB     = (float*)(YR + (size_t)NN * 128 * 4);   // 3.2 MB after G

    // ---- graph prep ----
    hipMemsetAsync(cursor, 0, (size_t)RR * NN * 4, stream);

    k_histp<<<dim3(CHK, RR, 2), 256, 0, stream>>>(src, dst, htmp);
    k_reduce<<<(2 * RR * 12512 + 255) / 256, 256, 0, stream>>>(htmp, outdeg, indeg);
    k_scanA<<<dim3(SCB, RR), 256, 0, stream>>>(indeg, bsum);
    k_scanB<<<RR, 256, 0, stream>>>(bsum, offs);
    k_scanC<<<dim3(SCB, RR), 256, 0, stream>>>(indeg, bsum, offs);
    k_norms<<<(RR * NN + 255) / 256, 256, 0, stream>>>(outdeg, indeg);
    int edgeBlocks = (RR * EE + 255) / 256;
    k_fillw<<<edgeBlocks, 256, 0, stream>>>(src, dst, offs, ns, cursor, csrw);
    k_prep<<<18, 256, 0, stream>>>(Wp1, Wp2, bp1, bp2, b2a, b2b, b3a, b3b, Mcat, cvec, bsums);
    k_fold<<<257, 256, 0, stream>>>(W2b, W3b, Mcat, bsums, FmatT, cfold);

    k_castx<<<(NN * 560 + 255) / 256, 256, 0, stream>>>(x2, x3, XH);
    k_wt2<<<dim3((256 * RR * 304 + 255) / 256, 2), 256, 0, stream>>>(W2a, W3a, WT2a, WT3a);

    // ---- phase a: chunked dual aggregation + paired GEMM -> hbuf23 (relu bf16) ----
    for (int c = 0; c < NN / CH; c++) {
        k_aggp<<<dim3(CH / 4, RR), 256, 0, stream>>>(XH, csrw, offs, nd, c * CH, Y2a, Y3a);
        k_gemm2<<<dim3((CH + 63) / 64, 4, 2), 256, 0, stream>>>(
            Y2a, Y3a, WT2a, WT3a, bsums, hbuf23, c * CH, CH);
    }

    // ---- phase b (folded): G = hbuf23 @ FmatT^T  [NN x 128] f32 ----
    k_gemm_bf<1><<<dim3((NN + 127) / 128, 4), 256, 0, stream>>>(
        hbuf23, 512, FmatT, 512, bsums, (const float*)nullptr, 0,
        (void*)G, 128, NN, 512, 0);

    // ---- projected aggregation -> AB, then decoder ----
    k_aggAB<<<NN / 4, 256, 0, stream>>>(csrw, offs, nd, G, cfold, cvec, AB);
    k_dec<<<(EDD + 255) / 256, 256, 0, stream>>>(dsrc, ddst, AB, out);
}